// Round 12
// baseline (1507.504 us; speedup 1.0000x reference)
//
#include <hip/hip_runtime.h>
#include <math.h>

#define N_ 64
#define T_ 256
#define I_ 512
#define H_ 1024

typedef unsigned short u16;
typedef unsigned int u32;
typedef short bf16x8 __attribute__((ext_vector_type(8)));
typedef float f32x4 __attribute__((ext_vector_type(4)));
typedef u16 u16x4 __attribute__((ext_vector_type(4)));

__device__ __forceinline__ u16 f2bf(float f) {
    union { float f; unsigned int u; } x; x.f = f;
    unsigned int r = (x.u + 0x7FFFu + ((x.u >> 16) & 1u)) >> 16;
    return (u16)r;
}
__device__ __forceinline__ float bf2f(u16 u) {
    union { unsigned int u; float f; } x; x.u = ((unsigned int)u) << 16;
    return x.f;
}
__device__ __forceinline__ float sigf(float v) {
    return 1.0f / (1.0f + __expf(-v));
}
__device__ __forceinline__ float tanhfast(float x) {
    float e = __expf(2.0f * x);
    return 1.0f - 2.0f / (e + 1.0f);   // NaN-free at +-inf
}

// aux=17 = SC0|SC1: bypass L1/L2, read at IC (device coherence point) [proven r7+]
__device__ __forceinline__ void gload_lds16_bypass(const void* g, void* l) {
    __builtin_amdgcn_global_load_lds(
        (__attribute__((address_space(1))) void*)(g),
        (__attribute__((address_space(3))) void*)(l), 16, 0, 17);
}
// cached variant (weights staging in GEMMs)
__device__ __forceinline__ void gload_lds16n(const void* g, void* l) {
    __builtin_amdgcn_global_load_lds(
        (__attribute__((address_space(1))) void*)(g),
        (__attribute__((address_space(3))) void*)(l), 16, 0, 0);
}

#define VMW(Ncnt) do { \
    asm volatile("s_waitcnt vmcnt(" #Ncnt ")" ::: "memory"); \
    __builtin_amdgcn_sched_barrier(0); } while (0)

// Per-group h fragment layout, LANE-MAJOR (conflict-free):
// elem(nloc 0..15, k 0..1023) = (k>>5)*512 + ((k>>3)&3)*128 + nloc*8 + (k&7).
// Wave read of chunk kk = contiguous 1KB at kk*1024 + lane*16 -> 0 conflicts.
__device__ __forceinline__ int hfrag16(int nloc, int k) {
    return ((k >> 5) << 9) + (((k >> 3) & 3) << 7) + (nloc << 3) + (k & 7);
}

// ---------------- prep kernels ----------------

// Packed row rp = j*4+g : [W_ih[g*H+j][0:512] ; W_hh[g*H+j][0:1024]] bf16
__global__ __launch_bounds__(256) void pack_weights(
    const float* __restrict__ W_ih, const float* __restrict__ W_hh,
    const float* __restrict__ b_ih, const float* __restrict__ b_hh,
    u16* __restrict__ Wp, float* __restrict__ bp)
{
    const int rp = blockIdx.x;            // 0..4095
    const int j = rp >> 2, g = rp & 3;
    const int src = g * H_ + j;
    const float* wi = W_ih + (size_t)src * I_;
    const float* wh = W_hh + (size_t)src * H_;
    u16* dst = Wp + (size_t)rp * (I_ + H_);
    for (int k = threadIdx.x; k < I_; k += 256) dst[k] = f2bf(wi[k]);
    for (int k = threadIdx.x; k < H_; k += 256) dst[I_ + k] = f2bf(wh[k]);
    if (threadIdx.x == 0) bp[rp] = b_ih[src] + b_hh[src];
}

__global__ __launch_bounds__(256) void conv_x(
    const float* __restrict__ x, u16* __restrict__ x_tb)
{
    const int t = blockIdx.x, n = blockIdx.y;
    const float* s = x + ((size_t)n * T_ + t) * I_;
    u16* d = x_tb + ((size_t)t * N_ + n) * I_;
    for (int k = threadIdx.x; k < I_; k += 256) d[k] = f2bf(s[k]);
}

__global__ __launch_bounds__(256) void conv_wout(
    const float* __restrict__ W, u16* __restrict__ Wb)
{
    const size_t base = (size_t)blockIdx.x * 1024 + threadIdx.x;
    #pragma unroll
    for (int q = 0; q < 4; ++q) Wb[base + q * 256] = f2bf(W[base + q * 256]);
}

__global__ __launch_bounds__(64) void init_rT(
    const int* __restrict__ is_init, float* __restrict__ rT)
{
    const int t = blockIdx.x;    // 0..256
    const int n = threadIdx.x;   // 0..63
    float r = 1.0f;
    if (t < T_) r = (is_init[n * T_ + t] != 0) ? 0.0f : 1.0f;
    rT[t * 64 + n] = r;
}

// hbuf[group n>>4][parity 0] = bf16(hx[:,0]*r[0]) in per-group fragment layout
__global__ __launch_bounds__(256) void init_h0(
    const float* __restrict__ hx, const int* __restrict__ is_init,
    u16* __restrict__ hbuf)
{
    const int idx = blockIdx.x * 256 + threadIdx.x;   // 65536
    const int n = idx >> 10, j = idx & (H_ - 1);
    const float r = (is_init[n * T_] != 0) ? 0.0f : 1.0f;
    hbuf[(n >> 4) * 32768 + hfrag16(n & 15, j)] = f2bf(hx[(size_t)n * T_ * H_ + j] * r);
}

// ---------------- x-gate precompute: 256x256-tile GEMM, LDS-dbuf B ----------
// Xg[row=(t*64+n)][p] = bf16( x_tb[row,:512]·Wp[p,:512] + bp[p] ).
__global__ __launch_bounds__(512) __attribute__((amdgpu_waves_per_eu(2, 2)))
void xgates_mfma(
    const u16* __restrict__ x_tb,   // [16384][512]
    const u16* __restrict__ Wp,     // [4096][1536] (x-part = first 512)
    const float* __restrict__ bp,   // [4096]
    u16* __restrict__ Xg)           // [16384][4096]
{
    __shared__ u16 bls[2][8192];    // 2 x 16KB, lane-major per 16-col tile
    const int bx = blockIdx.x, by = blockIdx.y;
    const int tid = threadIdx.x;
    const int v = tid >> 6, l = tid & 63;
    const int l15 = l & 15, lh = l >> 4;
    const int rowb = bx * 256 + v * 32;
    const int colb = by * 256;

    const u16* ap0 = x_tb + (size_t)(rowb + l15) * I_ + lh * 8;
    const u16* ap1 = x_tb + (size_t)(rowb + 16 + l15) * I_ + lh * 8;
    const u16* bs0 = Wp + (size_t)(colb + (2 * v) * 16 + l15) * 1536 + lh * 8;
    const u16* bs1 = Wp + (size_t)(colb + (2 * v + 1) * 16 + l15) * 1536 + lh * 8;

    f32x4 acc[2][16];
    #pragma unroll
    for (int m = 0; m < 2; ++m)
        #pragma unroll
        for (int nt = 0; nt < 16; ++nt) acc[m][nt] = f32x4{0.f, 0.f, 0.f, 0.f};

#define STAGEX(S, B) do { \
    gload_lds16n(bs0 + (S) * 32, (char*)bls[B] + (2 * v) * 1024); \
    gload_lds16n(bs1 + (S) * 32, (char*)bls[B] + (2 * v + 1) * 1024); } while (0)

    STAGEX(0, 0);
    VMW(0); __syncthreads();
    int buf = 0;
    for (int s = 0; s < 16; ++s) {
        if (s < 15) STAGEX(s + 1, buf ^ 1);
        bf16x8 a0 = *(const bf16x8*)(ap0 + s * 32);
        bf16x8 a1 = *(const bf16x8*)(ap1 + s * 32);
        const char* bb = (const char*)bls[buf];
        #pragma unroll
        for (int nt = 0; nt < 16; ++nt) {
            bf16x8 bfr = *(const bf16x8*)(bb + nt * 1024 + l * 16);
            acc[0][nt] = __builtin_amdgcn_mfma_f32_16x16x32_bf16(a0, bfr, acc[0][nt], 0, 0, 0);
            acc[1][nt] = __builtin_amdgcn_mfma_f32_16x16x32_bf16(a1, bfr, acc[1][nt], 0, 0, 0);
        }
        VMW(0); __syncthreads();
        buf ^= 1;
    }
#undef STAGEX

    #pragma unroll
    for (int nt = 0; nt < 16; ++nt) {
        const int col = colb + nt * 16 + l15;
        const float bo = bp[col];
        #pragma unroll
        for (int mt = 0; mt < 2; ++mt)
            #pragma unroll
            for (int rg = 0; rg < 4; ++rg) {
                const int row = rowb + mt * 16 + lh * 4 + rg;
                Xg[(size_t)row * 4096 + col] = f2bf(acc[mt][nt][rg] + bo);
            }
    }
}

// ---------------- persistent LSTM scan: 32 unit-blocks x 4 batch-groups ------
// [proven r11 structure] + OPAQUE-PINNED Wh registers (defeats load-sinking).
__global__ __launch_bounds__(512) __attribute__((amdgpu_waves_per_eu(2, 2)))
void lstm_seq(
    const u16* __restrict__ Xg,      // [16384][4096] bf16 (x-gates + bias)
    const u16* __restrict__ Wp,      // [4096][1536]
    const float* __restrict__ rT,    // [257][64]
    const float* __restrict__ cx,    // (N,T,H) fp32
    u16* __restrict__ hbuf,          // [4][2][16384] bf16, per-group frag order
    float* __restrict__ c_final,     // [64][1024] fp32
    u16* __restrict__ hs,            // [64][256][1024] bf16 (in out2 region)
    u32* __restrict__ flags)         // [4][32] spaced x16 u32
{
    __shared__ u16 zls[16384];       // 32 KB: group h, lane-major frag order
    const int tid = threadIdx.x;
    const int v = tid >> 6, l = tid & 63;
    const int l15 = l & 15, lh = l >> 4;
    const int u = blockIdx.x & 31, b = blockIdx.x >> 5;
    const int rowbase = u * 128 + v * 16;

    // pin h-part weights: Wh[kk] = packed row (rowbase + l15), k = 512+kk*32+lh*8
    bf16x8 Wh[32];
    #pragma unroll
    for (int kk = 0; kk < 32; ++kk) {
        Wh[kk] = *(const bf16x8*)(
            Wp + (size_t)(rowbase + l15) * 1536 + I_ + kk * 32 + lh * 8);
        // OPAQUE PIN: make Wh[kk] an asm-produced value so the compiler cannot
        // sink/rematerialize the load inside the T-loop (r11: VGPR=88 showed
        // 256 KB/WG/step of L2 weight re-reads on the critical path).
        asm volatile("" : "+v"(Wh[kk]));
    }

    const int jb = u * 32 + v * 4 + lh;   // this lane's unit
    const int n = b * 16 + l15;           // this lane's batch

    float cr = cx[(size_t)n * T_ * H_ + jb];

    u16* gbase = hbuf + (size_t)b * 32768;
    u32* gflags = flags + b * 32 * 16;
    const int zoff = l * 16;              // lane-major: contiguous 1KB per wave read

    for (int t = 0; t < T_; ++t) {
        const u16* hin = gbase + (t & 1) * 16384;
        u16*       hout = gbase + ((t & 1) ^ 1) * 16384;

        if (t > 0) {
            if (tid < 32) {
                while (__hip_atomic_load(gflags + tid * 16, __ATOMIC_RELAXED,
                                         __HIP_MEMORY_SCOPE_AGENT) < (u32)t)
                    __builtin_amdgcn_s_sleep(1);
            }
            __syncthreads();
        }

        // stage group h (32 KB) -> LDS: wave v stages chunks v*4..v*4+3
        {
            const char* hinb = (const char*)hin;
            char* lb = (char*)zls;
            #pragma unroll
            for (int i = 0; i < 4; ++i) {
                const int cb = (v * 4 + i) * 1024;
                gload_lds16_bypass(hinb + cb + l * 16, lb + cb);
            }
        }

        // x-gates + reset factors (cached loads, latency hidden under staging)
        const u16x4 xg = *(const u16x4*)(Xg + ((size_t)t * 64 + n) * 4096 + 4 * jb);
        const float rt = rT[t * 64 + n];
        const float rn = rT[(t + 1) * 64 + n];

        VMW(0);
        __syncthreads();

        // h-part matmul: K=1024, A = pinned weights, B = LDS (conflict-free)
        f32x4 acc = {0.f, 0.f, 0.f, 0.f};
        const char* zp = (const char*)zls;
        #pragma unroll
        for (int kk = 0; kk < 32; ++kk) {
            bf16x8 bz = *(const bf16x8*)(zp + zoff + kk * 1024);
            acc = __builtin_amdgcn_mfma_f32_16x16x32_bf16(Wh[kk], bz, acc, 0, 0, 0);
        }

        // epilogue: 1 cell/lane; gates i,f,g,o = acc[0..3] + Xg
        const float ig = acc[0] + bf2f(xg[0]);
        const float fg = acc[1] + bf2f(xg[1]);
        const float gg = acc[2] + bf2f(xg[2]);
        const float og = acc[3] + bf2f(xg[3]);
        const float cn = sigf(fg) * (cr * rt) + sigf(ig) * tanhfast(gg);
        const float hv = sigf(og) * tanhfast(cn);
        cr = cn;

        // pair units (jb even, jb+1) via lane+16; u32 write-through to group buf
        const float hvp = __shfl_down(hv, 16);
        u32 hsv = 0;
        if (!(lh & 1)) {
            const u32 ho = (u32)f2bf(hv * rn) | ((u32)f2bf(hvp * rn) << 16);
            hsv = (u32)f2bf(hv) | ((u32)f2bf(hvp) << 16);
            __hip_atomic_store((u32*)(hout + hfrag16(l15, jb)), ho,
                               __ATOMIC_RELAXED, __HIP_MEMORY_SCOPE_AGENT);
        }
        VMW(0);                      // release: h acked at IC
        __syncthreads();
        if (tid == 0)
            __hip_atomic_store(gflags + u * 16, (u32)(t + 1),
                               __ATOMIC_RELAXED, __HIP_MEMORY_SCOPE_AGENT);

        // hs (+ c_final at the end) AFTER the release — drains during next poll
        if (!(lh & 1))
            *(u32*)(hs + ((size_t)n * T_ + t) * H_ + jb) = hsv;
        if (t == T_ - 1)
            c_final[(size_t)n * H_ + jb] = cr;
    }
}

// ---------------- output projection: 256x256-tile GEMM + mish ----------------
__global__ __launch_bounds__(512) __attribute__((amdgpu_waves_per_eu(2, 2)))
void out_proj_mfma(
    const u16* __restrict__ hs,     // [16384][1024]
    const u16* __restrict__ Wo,     // [1024][1024]
    const float* __restrict__ b_out,
    float* __restrict__ out0)       // [16384][1024]
{
    __shared__ u16 bls[2][8192];    // 2 x 16KB
    const int bx = blockIdx.x, by = blockIdx.y;
    const int tid = threadIdx.x;
    const int v = tid >> 6, l = tid & 63;
    const int l15 = l & 15, lh = l >> 4;
    const int rowb = bx * 256 + v * 32;
    const int colb = by * 256;

    const u16* ap0 = hs + (size_t)(rowb + l15) * H_ + lh * 8;
    const u16* ap1 = hs + (size_t)(rowb + 16 + l15) * H_ + lh * 8;
    const u16* bs0 = Wo + (size_t)(colb + (2 * v) * 16 + l15) * H_ + lh * 8;
    const u16* bs1 = Wo + (size_t)(colb + (2 * v + 1) * 16 + l15) * H_ + lh * 8;

    f32x4 acc[2][16];
    #pragma unroll
    for (int m = 0; m < 2; ++m)
        #pragma unroll
        for (int nt = 0; nt < 16; ++nt) acc[m][nt] = f32x4{0.f, 0.f, 0.f, 0.f};

#define STAGEO(S, B) do { \
    gload_lds16n(bs0 + (S) * 32, (char*)bls[B] + (2 * v) * 1024); \
    gload_lds16n(bs1 + (S) * 32, (char*)bls[B] + (2 * v + 1) * 1024); } while (0)

    STAGEO(0, 0);
    VMW(0); __syncthreads();
    int buf = 0;
    for (int s = 0; s < 32; ++s) {
        if (s < 31) STAGEO(s + 1, buf ^ 1);
        bf16x8 a0 = *(const bf16x8*)(ap0 + s * 32);
        bf16x8 a1 = *(const bf16x8*)(ap1 + s * 32);
        const char* bb = (const char*)bls[buf];
        #pragma unroll
        for (int nt = 0; nt < 16; ++nt) {
            bf16x8 bfr = *(const bf16x8*)(bb + nt * 1024 + l * 16);
            acc[0][nt] = __builtin_amdgcn_mfma_f32_16x16x32_bf16(a0, bfr, acc[0][nt], 0, 0, 0);
            acc[1][nt] = __builtin_amdgcn_mfma_f32_16x16x32_bf16(a1, bfr, acc[1][nt], 0, 0, 0);
        }
        VMW(0); __syncthreads();
        buf ^= 1;
    }
#undef STAGEO

    #pragma unroll
    for (int nt = 0; nt < 16; ++nt) {
        const int col = colb + nt * 16 + l15;
        const float bo = b_out[col];
        #pragma unroll
        for (int mt = 0; mt < 2; ++mt)
            #pragma unroll
            for (int rg = 0; rg < 4; ++rg) {
                const int row = rowb + mt * 16 + lh * 4 + rg;
                const float y = acc[mt][nt][rg] + bo;
                const float sp = (y > 15.f) ? y : log1pf(__expf(y));
                out0[(size_t)row * H_ + col] = y * tanhfast(sp);
            }
    }
}

// out1 = broadcast hs[:,255,:]  (hs in out2 region — MUST run before bcast_c)
__global__ __launch_bounds__(256) void bcast_h(
    const u16* __restrict__ hs, float* __restrict__ out1)
{
    const size_t total = (size_t)N_ * T_ * H_;
    for (size_t idx = (size_t)blockIdx.x * 256 + threadIdx.x; idx < total;
         idx += (size_t)gridDim.x * 256) {
        const int n = (int)(idx >> 18);
        const int j = (int)(idx & (H_ - 1));
        out1[idx] = bf2f(hs[((size_t)n * T_ + (T_ - 1)) * H_ + j]);
    }
}

__global__ __launch_bounds__(256) void bcast_c(
    const float* __restrict__ c_final, float* __restrict__ out2)
{
    const size_t total = (size_t)N_ * T_ * H_;
    for (size_t idx = (size_t)blockIdx.x * 256 + threadIdx.x; idx < total;
         idx += (size_t)gridDim.x * 256) {
        const int n = (int)(idx >> 18);
        const int j = (int)(idx & (H_ - 1));
        out2[idx] = c_final[n * H_ + j];
    }
}

extern "C" void kernel_launch(void* const* d_in, const int* in_sizes, int n_in,
                              void* d_out, int out_size, void* d_ws, size_t ws_size,
                              hipStream_t stream) {
    const float* x      = (const float*)d_in[0];
    const int*   is_ini = (const int*)  d_in[1];
    const float* hx     = (const float*)d_in[2];
    const float* cx     = (const float*)d_in[3];
    const float* W_ih   = (const float*)d_in[4];
    const float* W_hh   = (const float*)d_in[5];
    const float* b_ih   = (const float*)d_in[6];
    const float* b_hh   = (const float*)d_in[7];
    const float* W_out  = (const float*)d_in[8];
    const float* b_out  = (const float*)d_in[9];

    float* out0 = (float*)d_out;
    float* out1 = out0 + (size_t)N_ * T_ * H_;
    float* out2 = out1 + (size_t)N_ * T_ * H_;

    char* ws = (char*)d_ws;
    u16*   x_tb    = (u16*)  (ws + 0);          // 16,777,216
    u16*   Wp      = (u16*)  (ws + 16777216);   // 12,582,912
    float* bp      = (float*)(ws + 29360128);   // 16,384
    u16*   Wo_b    = (u16*)  (ws + 29376512);   // 2,097,152
    u16*   hbuf    = (u16*)  (ws + 31473664);   // 262,144  [4][2][16384] u16
    float* c_final = (float*)(ws + 31735808);   // 262,144
    float* rT      = (float*)(ws + 31997952);   // 65,792
    u32*   flags   = (u32*)  (ws + 32063744);   // 8,192    [4][32] x16-spaced

    u16* Xg = (u16*)out0;   // 134.2 MB scratch spanning out0+out1 (exact fit);
                            // consumed by lstm_seq, then overwritten by outputs
    u16* hs = (u16*)out2;   // 33.5 MB scratch inside out2 region

    hipMemsetAsync(flags, 0, 8192, stream);
    pack_weights<<<4096, 256, 0, stream>>>(W_ih, W_hh, b_ih, b_hh, Wp, bp);
    conv_x<<<dim3(T_, N_), 256, 0, stream>>>(x, x_tb);
    conv_wout<<<1024, 256, 0, stream>>>(W_out, Wo_b);
    init_rT<<<T_ + 1, 64, 0, stream>>>(is_ini, rT);
    init_h0<<<256, 256, 0, stream>>>(hx, is_ini, hbuf);

    xgates_mfma<<<dim3(64, 16), 512, 0, stream>>>(x_tb, Wp, bp, Xg);

    lstm_seq<<<128, 512, 0, stream>>>(Xg, Wp, rT, cx, hbuf, c_final, hs, flags);

    out_proj_mfma<<<dim3(64, 4), 512, 0, stream>>>(hs, Wo_b, b_out, out0);
    bcast_h<<<2048, 256, 0, stream>>>(hs, out1);
    bcast_c<<<2048, 256, 0, stream>>>(c_final, out2);
}

// Round 13
// 1396.454 us; speedup vs baseline: 1.0795x; 1.0795x over previous
//
#include <hip/hip_runtime.h>
#include <math.h>

#define N_ 64
#define T_ 256
#define I_ 512
#define H_ 1024

typedef unsigned short u16;
typedef unsigned int u32;
typedef short bf16x8 __attribute__((ext_vector_type(8)));
typedef float f32x4 __attribute__((ext_vector_type(4)));
typedef u16 u16x4 __attribute__((ext_vector_type(4)));

__device__ __forceinline__ u16 f2bf(float f) {
    union { float f; unsigned int u; } x; x.f = f;
    unsigned int r = (x.u + 0x7FFFu + ((x.u >> 16) & 1u)) >> 16;
    return (u16)r;
}
__device__ __forceinline__ float bf2f(u16 u) {
    union { unsigned int u; float f; } x; x.u = ((unsigned int)u) << 16;
    return x.f;
}
__device__ __forceinline__ float sigf(float v) {
    return 1.0f / (1.0f + __expf(-v));
}
__device__ __forceinline__ float tanhfast(float x) {
    float e = __expf(2.0f * x);
    return 1.0f - 2.0f / (e + 1.0f);   // NaN-free at +-inf
}

// aux=17 = SC0|SC1: bypass L1/L2, read at IC (device coherence point) [proven r7+]
__device__ __forceinline__ void gload_lds16_bypass(const void* g, void* l) {
    __builtin_amdgcn_global_load_lds(
        (__attribute__((address_space(1))) void*)(g),
        (__attribute__((address_space(3))) void*)(l), 16, 0, 17);
}
// cached variant (weight staging)
__device__ __forceinline__ void gload_lds16n(const void* g, void* l) {
    __builtin_amdgcn_global_load_lds(
        (__attribute__((address_space(1))) void*)(g),
        (__attribute__((address_space(3))) void*)(l), 16, 0, 0);
}

#define VMW(Ncnt) do { \
    asm volatile("s_waitcnt vmcnt(" #Ncnt ")" ::: "memory"); \
    __builtin_amdgcn_sched_barrier(0); } while (0)

// Per-group h fragment layout, LANE-MAJOR (conflict-free) [proven r11]:
// elem(nloc 0..15, k 0..1023) = (k>>5)*512 + ((k>>3)&3)*128 + nloc*8 + (k&7).
__device__ __forceinline__ int hfrag16(int nloc, int k) {
    return ((k >> 5) << 9) + (((k >> 3) & 3) << 7) + (nloc << 3) + (k & 7);
}

// ---------------- prep kernels ----------------

// Packed row rp = j*4+g : [W_ih[g*H+j][0:512] ; W_hh[g*H+j][0:1024]] bf16
__global__ __launch_bounds__(256) void pack_weights(
    const float* __restrict__ W_ih, const float* __restrict__ W_hh,
    const float* __restrict__ b_ih, const float* __restrict__ b_hh,
    u16* __restrict__ Wp, float* __restrict__ bp)
{
    const int rp = blockIdx.x;            // 0..4095
    const int j = rp >> 2, g = rp & 3;
    const int src = g * H_ + j;
    const float* wi = W_ih + (size_t)src * I_;
    const float* wh = W_hh + (size_t)src * H_;
    u16* dst = Wp + (size_t)rp * (I_ + H_);
    for (int k = threadIdx.x; k < I_; k += 256) dst[k] = f2bf(wi[k]);
    for (int k = threadIdx.x; k < H_; k += 256) dst[I_ + k] = f2bf(wh[k]);
    if (threadIdx.x == 0) bp[rp] = b_ih[src] + b_hh[src];
}

__global__ __launch_bounds__(256) void conv_x(
    const float* __restrict__ x, u16* __restrict__ x_tb)
{
    const int t = blockIdx.x, n = blockIdx.y;
    const float* s = x + ((size_t)n * T_ + t) * I_;
    u16* d = x_tb + ((size_t)t * N_ + n) * I_;
    for (int k = threadIdx.x; k < I_; k += 256) d[k] = f2bf(s[k]);
}

__global__ __launch_bounds__(256) void conv_wout(
    const float* __restrict__ W, u16* __restrict__ Wb)
{
    const size_t base = (size_t)blockIdx.x * 1024 + threadIdx.x;
    #pragma unroll
    for (int q = 0; q < 4; ++q) Wb[base + q * 256] = f2bf(W[base + q * 256]);
}

__global__ __launch_bounds__(64) void init_rT(
    const int* __restrict__ is_init, float* __restrict__ rT)
{
    const int t = blockIdx.x;    // 0..256
    const int n = threadIdx.x;   // 0..63
    float r = 1.0f;
    if (t < T_) r = (is_init[n * T_ + t] != 0) ? 0.0f : 1.0f;
    rT[t * 64 + n] = r;
}

// hbuf[group n>>4][parity 0] = bf16(hx[:,0]*r[0]) in per-group fragment layout
__global__ __launch_bounds__(256) void init_h0(
    const float* __restrict__ hx, const int* __restrict__ is_init,
    u16* __restrict__ hbuf)
{
    const int idx = blockIdx.x * 256 + threadIdx.x;   // 65536
    const int n = idx >> 10, j = idx & (H_ - 1);
    const float r = (is_init[n * T_] != 0) ? 0.0f : 1.0f;
    hbuf[(n >> 4) * 32768 + hfrag16(n & 15, j)] = f2bf(hx[(size_t)n * T_ * H_ + j] * r);
}

// ---------------- x-gate precompute: 256x256-tile GEMM [proven r11] ----------
__global__ __launch_bounds__(512) __attribute__((amdgpu_waves_per_eu(2, 2)))
void xgates_mfma(
    const u16* __restrict__ x_tb,   // [16384][512]
    const u16* __restrict__ Wp,     // [4096][1536] (x-part = first 512)
    const float* __restrict__ bp,   // [4096]
    u16* __restrict__ Xg)           // [16384][4096]
{
    __shared__ u16 bls[2][8192];    // 2 x 16KB, lane-major per 16-col tile
    const int bx = blockIdx.x, by = blockIdx.y;
    const int tid = threadIdx.x;
    const int v = tid >> 6, l = tid & 63;
    const int l15 = l & 15, lh = l >> 4;
    const int rowb = bx * 256 + v * 32;
    const int colb = by * 256;

    const u16* ap0 = x_tb + (size_t)(rowb + l15) * I_ + lh * 8;
    const u16* ap1 = x_tb + (size_t)(rowb + 16 + l15) * I_ + lh * 8;
    const u16* bs0 = Wp + (size_t)(colb + (2 * v) * 16 + l15) * 1536 + lh * 8;
    const u16* bs1 = Wp + (size_t)(colb + (2 * v + 1) * 16 + l15) * 1536 + lh * 8;

    f32x4 acc[2][16];
    #pragma unroll
    for (int m = 0; m < 2; ++m)
        #pragma unroll
        for (int nt = 0; nt < 16; ++nt) acc[m][nt] = f32x4{0.f, 0.f, 0.f, 0.f};

#define STAGEX(S, B) do { \
    gload_lds16n(bs0 + (S) * 32, (char*)bls[B] + (2 * v) * 1024); \
    gload_lds16n(bs1 + (S) * 32, (char*)bls[B] + (2 * v + 1) * 1024); } while (0)

    STAGEX(0, 0);
    VMW(0); __syncthreads();
    int buf = 0;
    for (int s = 0; s < 16; ++s) {
        if (s < 15) STAGEX(s + 1, buf ^ 1);
        bf16x8 a0 = *(const bf16x8*)(ap0 + s * 32);
        bf16x8 a1 = *(const bf16x8*)(ap1 + s * 32);
        const char* bb = (const char*)bls[buf];
        #pragma unroll
        for (int nt = 0; nt < 16; ++nt) {
            bf16x8 bfr = *(const bf16x8*)(bb + nt * 1024 + l * 16);
            acc[0][nt] = __builtin_amdgcn_mfma_f32_16x16x32_bf16(a0, bfr, acc[0][nt], 0, 0, 0);
            acc[1][nt] = __builtin_amdgcn_mfma_f32_16x16x32_bf16(a1, bfr, acc[1][nt], 0, 0, 0);
        }
        VMW(0); __syncthreads();
        buf ^= 1;
    }
#undef STAGEX

    #pragma unroll
    for (int nt = 0; nt < 16; ++nt) {
        const int col = colb + nt * 16 + l15;
        const float bo = bp[col];
        #pragma unroll
        for (int mt = 0; mt < 2; ++mt)
            #pragma unroll
            for (int rg = 0; rg < 4; ++rg) {
                const int row = rowb + mt * 16 + lh * 4 + rg;
                Xg[(size_t)row * 4096 + col] = f2bf(acc[mt][nt][rg] + bo);
            }
    }
}

// ---------------- persistent LSTM scan: weights in LDS -----------------------
// 256 WGs x 256 thr (4 waves), LDS = 128KB weights + 32KB h = 160KB -> 1 WG/CU,
// all 256 resident (capacity-guaranteed, no placement assumptions).
// WG(u = bid&63, b = bid>>6): units u*16..+15 (packed rows u*64..+63), batches
// b*16..+15. Wave v: rows u*64+v*16..+15 (1 M-frag) x 16 batches (1 N-frag).
// Per-step: NO global weight traffic — A from LDS, B from LDS (both lane-major,
// conflict-free). Sync per 64-WG group via IC flags [proven r9-r12 protocol].
__global__ __launch_bounds__(256, 1) void lstm_seq(
    const u16* __restrict__ Xg,      // [16384][4096] bf16 (x-gates + bias)
    const u16* __restrict__ Wp,      // [4096][1536]
    const float* __restrict__ rT,    // [257][64]
    const float* __restrict__ cx,    // (N,T,H) fp32
    u16* __restrict__ hbuf,          // [4][2][16384] bf16, per-group frag order
    float* __restrict__ c_final,     // [64][1024] fp32
    u16* __restrict__ hs,            // [64][256][1024] bf16 (in out2 region)
    u32* __restrict__ flags)         // [4][64] spaced x16 u32
{
    __shared__ u16 wls[65536];       // 128 KB: h-part weights, per-wave lane-major
    __shared__ u16 zls[16384];       // 32 KB: group h, lane-major frag order
    const int tid = threadIdx.x;
    const int v = tid >> 6, l = tid & 63;
    const int l15 = l & 15, lh = l >> 4;
    const int u = blockIdx.x & 63, b = blockIdx.x >> 6;
    const int rowbase = u * 64 + v * 16;

    // ---- preload h-part weights into LDS (once) ----
    // wave v, chunk kk -> wls bytes [v*32768 + kk*1024 .. +1023]; lane l's 16B
    // slot (HW dest = base + lane*16) holds row (rowbase+l15), k-slice lh.
    {
        const u16* src = Wp + (size_t)(rowbase + l15) * 1536 + I_ + lh * 8;
        char* dst = (char*)wls + v * 32768;
        #pragma unroll
        for (int kk = 0; kk < 32; ++kk)
            gload_lds16n(src + kk * 32, dst + kk * 1024);
    }

    const int jb = u * 16 + v * 4 + lh;   // this lane's unit
    const int n = b * 16 + l15;           // this lane's batch

    float cr = cx[(size_t)n * T_ * H_ + jb];

    u16* gbase = hbuf + (size_t)b * 32768;
    u32* gflags = flags + b * 64 * 16;
    const char* wlsb = (const char*)wls + v * 32768;
    const char* zlsb = (const char*)zls;

    VMW(0);
    __syncthreads();

    for (int t = 0; t < T_; ++t) {
        const u16* hin = gbase + (t & 1) * 16384;
        u16*       hout = gbase + ((t & 1) ^ 1) * 16384;

        if (t > 0) {
            if (tid < 64) {
                while (__hip_atomic_load(gflags + tid * 16, __ATOMIC_RELAXED,
                                         __HIP_MEMORY_SCOPE_AGENT) < (u32)t)
                    __builtin_amdgcn_s_sleep(1);
            }
            __syncthreads();
        }

        // stage group h (32 KB) -> LDS: wave v stages chunks v*8..v*8+7
        {
            const char* hinb = (const char*)hin;
            char* lb = (char*)zls;
            #pragma unroll
            for (int i = 0; i < 8; ++i) {
                const int cb = (v * 8 + i) * 1024;
                gload_lds16_bypass(hinb + cb + l * 16, lb + cb);
            }
        }

        // x-gates + reset factors (cached loads, hidden under staging)
        const u16x4 xg = *(const u16x4*)(Xg + ((size_t)t * 64 + n) * 4096 + 4 * jb);
        const float rt = rT[t * 64 + n];
        const float rn = rT[(t + 1) * 64 + n];

        VMW(0);
        __syncthreads();

        // h-part matmul: K=1024, A from LDS weights, B from LDS h (both
        // contiguous-1KB-per-wave reads -> zero bank conflicts)
        f32x4 acc = {0.f, 0.f, 0.f, 0.f};
        #pragma unroll
        for (int kk = 0; kk < 32; ++kk) {
            bf16x8 wf = *(const bf16x8*)(wlsb + kk * 1024 + l * 16);
            bf16x8 bz = *(const bf16x8*)(zlsb + kk * 1024 + l * 16);
            acc = __builtin_amdgcn_mfma_f32_16x16x32_bf16(wf, bz, acc, 0, 0, 0);
        }

        // epilogue: 1 cell/lane; gates i,f,g,o = acc[0..3] + Xg
        const float ig = acc[0] + bf2f(xg[0]);
        const float fg = acc[1] + bf2f(xg[1]);
        const float gg = acc[2] + bf2f(xg[2]);
        const float og = acc[3] + bf2f(xg[3]);
        const float cn = sigf(fg) * (cr * rt) + sigf(ig) * tanhfast(gg);
        const float hv = sigf(og) * tanhfast(cn);
        cr = cn;

        // pair units (jb even, jb+1 via lane+16); u32 write-through to group buf
        const float hvp = __shfl_down(hv, 16);
        u32 hsv = 0;
        if (!(lh & 1)) {
            const u32 ho = (u32)f2bf(hv * rn) | ((u32)f2bf(hvp * rn) << 16);
            hsv = (u32)f2bf(hv) | ((u32)f2bf(hvp) << 16);
            __hip_atomic_store((u32*)(hout + hfrag16(l15, jb)), ho,
                               __ATOMIC_RELAXED, __HIP_MEMORY_SCOPE_AGENT);
        }
        VMW(0);                      // release: h acked at IC
        __syncthreads();
        if (tid == 0)
            __hip_atomic_store(gflags + u * 16, (u32)(t + 1),
                               __ATOMIC_RELAXED, __HIP_MEMORY_SCOPE_AGENT);

        // hs (+ c_final at the end) AFTER the release — drains during next poll
        if (!(lh & 1))
            *(u32*)(hs + ((size_t)n * T_ + t) * H_ + jb) = hsv;
        if (t == T_ - 1)
            c_final[(size_t)n * H_ + jb] = cr;
    }
}

// ---------------- output projection: 256x256-tile GEMM + mish [proven r11] ---
__global__ __launch_bounds__(512) __attribute__((amdgpu_waves_per_eu(2, 2)))
void out_proj_mfma(
    const u16* __restrict__ hs,     // [16384][1024]
    const u16* __restrict__ Wo,     // [1024][1024]
    const float* __restrict__ b_out,
    float* __restrict__ out0)       // [16384][1024]
{
    __shared__ u16 bls[2][8192];    // 2 x 16KB
    const int bx = blockIdx.x, by = blockIdx.y;
    const int tid = threadIdx.x;
    const int v = tid >> 6, l = tid & 63;
    const int l15 = l & 15, lh = l >> 4;
    const int rowb = bx * 256 + v * 32;
    const int colb = by * 256;

    const u16* ap0 = hs + (size_t)(rowb + l15) * H_ + lh * 8;
    const u16* ap1 = hs + (size_t)(rowb + 16 + l15) * H_ + lh * 8;
    const u16* bs0 = Wo + (size_t)(colb + (2 * v) * 16 + l15) * H_ + lh * 8;
    const u16* bs1 = Wo + (size_t)(colb + (2 * v + 1) * 16 + l15) * H_ + lh * 8;

    f32x4 acc[2][16];
    #pragma unroll
    for (int m = 0; m < 2; ++m)
        #pragma unroll
        for (int nt = 0; nt < 16; ++nt) acc[m][nt] = f32x4{0.f, 0.f, 0.f, 0.f};

#define STAGEO(S, B) do { \
    gload_lds16n(bs0 + (S) * 32, (char*)bls[B] + (2 * v) * 1024); \
    gload_lds16n(bs1 + (S) * 32, (char*)bls[B] + (2 * v + 1) * 1024); } while (0)

    STAGEO(0, 0);
    VMW(0); __syncthreads();
    int buf = 0;
    for (int s = 0; s < 32; ++s) {
        if (s < 31) STAGEO(s + 1, buf ^ 1);
        bf16x8 a0 = *(const bf16x8*)(ap0 + s * 32);
        bf16x8 a1 = *(const bf16x8*)(ap1 + s * 32);
        const char* bb = (const char*)bls[buf];
        #pragma unroll
        for (int nt = 0; nt < 16; ++nt) {
            bf16x8 bfr = *(const bf16x8*)(bb + nt * 1024 + l * 16);
            acc[0][nt] = __builtin_amdgcn_mfma_f32_16x16x32_bf16(a0, bfr, acc[0][nt], 0, 0, 0);
            acc[1][nt] = __builtin_amdgcn_mfma_f32_16x16x32_bf16(a1, bfr, acc[1][nt], 0, 0, 0);
        }
        VMW(0); __syncthreads();
        buf ^= 1;
    }
#undef STAGEO

    #pragma unroll
    for (int nt = 0; nt < 16; ++nt) {
        const int col = colb + nt * 16 + l15;
        const float bo = b_out[col];
        #pragma unroll
        for (int mt = 0; mt < 2; ++mt)
            #pragma unroll
            for (int rg = 0; rg < 4; ++rg) {
                const int row = rowb + mt * 16 + lh * 4 + rg;
                const float y = acc[mt][nt][rg] + bo;
                const float sp = (y > 15.f) ? y : log1pf(__expf(y));
                out0[(size_t)row * H_ + col] = y * tanhfast(sp);
            }
    }
}

// out1 = broadcast hs[:,255,:]  (hs in out2 region — MUST run before bcast_c)
__global__ __launch_bounds__(256) void bcast_h(
    const u16* __restrict__ hs, float* __restrict__ out1)
{
    const size_t total = (size_t)N_ * T_ * H_;
    for (size_t idx = (size_t)blockIdx.x * 256 + threadIdx.x; idx < total;
         idx += (size_t)gridDim.x * 256) {
        const int n = (int)(idx >> 18);
        const int j = (int)(idx & (H_ - 1));
        out1[idx] = bf2f(hs[((size_t)n * T_ + (T_ - 1)) * H_ + j]);
    }
}

__global__ __launch_bounds__(256) void bcast_c(
    const float* __restrict__ c_final, float* __restrict__ out2)
{
    const size_t total = (size_t)N_ * T_ * H_;
    for (size_t idx = (size_t)blockIdx.x * 256 + threadIdx.x; idx < total;
         idx += (size_t)gridDim.x * 256) {
        const int n = (int)(idx >> 18);
        const int j = (int)(idx & (H_ - 1));
        out2[idx] = c_final[n * H_ + j];
    }
}

extern "C" void kernel_launch(void* const* d_in, const int* in_sizes, int n_in,
                              void* d_out, int out_size, void* d_ws, size_t ws_size,
                              hipStream_t stream) {
    const float* x      = (const float*)d_in[0];
    const int*   is_ini = (const int*)  d_in[1];
    const float* hx     = (const float*)d_in[2];
    const float* cx     = (const float*)d_in[3];
    const float* W_ih   = (const float*)d_in[4];
    const float* W_hh   = (const float*)d_in[5];
    const float* b_ih   = (const float*)d_in[6];
    const float* b_hh   = (const float*)d_in[7];
    const float* W_out  = (const float*)d_in[8];
    const float* b_out  = (const float*)d_in[9];

    float* out0 = (float*)d_out;
    float* out1 = out0 + (size_t)N_ * T_ * H_;
    float* out2 = out1 + (size_t)N_ * T_ * H_;

    char* ws = (char*)d_ws;
    u16*   x_tb    = (u16*)  (ws + 0);          // 16,777,216
    u16*   Wp      = (u16*)  (ws + 16777216);   // 12,582,912
    float* bp      = (float*)(ws + 29360128);   // 16,384
    u16*   Wo_b    = (u16*)  (ws + 29376512);   // 2,097,152
    u16*   hbuf    = (u16*)  (ws + 31473664);   // 262,144  [4][2][16384] u16
    float* c_final = (float*)(ws + 31735808);   // 262,144
    float* rT      = (float*)(ws + 31997952);   // 65,792
    u32*   flags   = (u32*)  (ws + 32063744);   // 16,384   [4][64] x16-spaced

    u16* Xg = (u16*)out0;   // 134.2 MB scratch spanning out0+out1 (exact fit);
                            // consumed by lstm_seq, then overwritten by outputs
    u16* hs = (u16*)out2;   // 33.5 MB scratch inside out2 region

    hipMemsetAsync(flags, 0, 16384, stream);
    pack_weights<<<4096, 256, 0, stream>>>(W_ih, W_hh, b_ih, b_hh, Wp, bp);
    conv_x<<<dim3(T_, N_), 256, 0, stream>>>(x, x_tb);
    conv_wout<<<1024, 256, 0, stream>>>(W_out, Wo_b);
    init_rT<<<T_ + 1, 64, 0, stream>>>(is_ini, rT);
    init_h0<<<256, 256, 0, stream>>>(hx, is_ini, hbuf);

    xgates_mfma<<<dim3(64, 16), 512, 0, stream>>>(x_tb, Wp, bp, Xg);

    lstm_seq<<<256, 256, 0, stream>>>(Xg, Wp, rT, cx, hbuf, c_final, hs, flags);

    out_proj_mfma<<<dim3(64, 4), 512, 0, stream>>>(hs, Wo_b, b_out, out0);
    bcast_h<<<2048, 256, 0, stream>>>(hs, out1);
    bcast_c<<<2048, 256, 0, stream>>>(c_final, out2);
}

// Round 14
// 1286.514 us; speedup vs baseline: 1.1718x; 1.0855x over previous
//
#include <hip/hip_runtime.h>
#include <math.h>

#define N_ 64
#define T_ 256
#define I_ 512
#define H_ 1024

typedef unsigned short u16;
typedef unsigned int u32;
typedef short bf16x8 __attribute__((ext_vector_type(8)));
typedef float f32x4 __attribute__((ext_vector_type(4)));
typedef u16 u16x4 __attribute__((ext_vector_type(4)));

__device__ __forceinline__ u16 f2bf(float f) {
    union { float f; unsigned int u; } x; x.f = f;
    unsigned int r = (x.u + 0x7FFFu + ((x.u >> 16) & 1u)) >> 16;
    return (u16)r;
}
__device__ __forceinline__ float bf2f(u16 u) {
    union { unsigned int u; float f; } x; x.u = ((unsigned int)u) << 16;
    return x.f;
}
__device__ __forceinline__ float sigf(float v) {
    return 1.0f / (1.0f + __expf(-v));
}
__device__ __forceinline__ float tanhfast(float x) {
    float e = __expf(2.0f * x);
    return 1.0f - 2.0f / (e + 1.0f);   // NaN-free at +-inf
}

// aux=17 = SC0|SC1: bypass L1/L2, read at IC (device coherence point) [proven r7+]
__device__ __forceinline__ void gload_lds16_bypass(const void* g, void* l) {
    __builtin_amdgcn_global_load_lds(
        (__attribute__((address_space(1))) void*)(g),
        (__attribute__((address_space(3))) void*)(l), 16, 0, 17);
}
// cached variant (weight staging)
__device__ __forceinline__ void gload_lds16n(const void* g, void* l) {
    __builtin_amdgcn_global_load_lds(
        (__attribute__((address_space(1))) void*)(g),
        (__attribute__((address_space(3))) void*)(l), 16, 0, 0);
}

#define VMW(Ncnt) do { \
    asm volatile("s_waitcnt vmcnt(" #Ncnt ")" ::: "memory"); \
    __builtin_amdgcn_sched_barrier(0); } while (0)

// c storage split: n<32 -> cA (upper half of out2), n>=32 -> cB (ws)
__device__ __forceinline__ float* c_ptr(int n, int t, int j, float* cA, float* cB) {
    return (n < 32) ? (cA + (((size_t)(n * 256 + t)) << 10) + j)
                    : (cB + (((size_t)((n - 32) * 256 + t)) << 10) + j);
}

// ---------------- prep kernels ----------------

// Packed row rp = j*4+g : [W_ih[g*H+j][0:512] ; W_hh[g*H+j][0:1024]] bf16
__global__ __launch_bounds__(256) void pack_weights(
    const float* __restrict__ W_ih, const float* __restrict__ W_hh,
    const float* __restrict__ b_ih, const float* __restrict__ b_hh,
    u16* __restrict__ Wp, float* __restrict__ bp)
{
    const int rp = blockIdx.x;            // 0..4095
    const int j = rp >> 2, g = rp & 3;
    const int src = g * H_ + j;
    const float* wi = W_ih + (size_t)src * I_;
    const float* wh = W_hh + (size_t)src * H_;
    u16* dst = Wp + (size_t)rp * (I_ + H_);
    for (int k = threadIdx.x; k < I_; k += 256) dst[k] = f2bf(wi[k]);
    for (int k = threadIdx.x; k < H_; k += 256) dst[I_ + k] = f2bf(wh[k]);
    if (threadIdx.x == 0) bp[rp] = b_ih[src] + b_hh[src];
}

__global__ __launch_bounds__(256) void conv_x(
    const float* __restrict__ x, u16* __restrict__ x_tb)
{
    const int t = blockIdx.x, n = blockIdx.y;
    const float* s = x + ((size_t)n * T_ + t) * I_;
    u16* d = x_tb + ((size_t)t * N_ + n) * I_;
    for (int k = threadIdx.x; k < I_; k += 256) d[k] = f2bf(s[k]);
}

__global__ __launch_bounds__(256) void conv_wout(
    const float* __restrict__ W, u16* __restrict__ Wb)
{
    const size_t base = (size_t)blockIdx.x * 1024 + threadIdx.x;
    #pragma unroll
    for (int q = 0; q < 4; ++q) Wb[base + q * 256] = f2bf(W[base + q * 256]);
}

// hxbf[n][j] = bf16(hx[n,0,j])   (UNscaled; only read by rows with r=1)
__global__ __launch_bounds__(256) void conv_hx(
    const float* __restrict__ hx, u16* __restrict__ hxbf)
{
    const int idx = blockIdx.x * 256 + threadIdx.x;   // 65536
    const int n = idx >> 10, j = idx & (H_ - 1);
    hxbf[idx] = f2bf(hx[(size_t)n * T_ * H_ + j]);
}

// rel[n,t] = 0 if is_init (reset: h_prev=c_prev=0), else rel[n,t-1]+1 (rel[n,-1]=0).
// counts[g][rel]++ for CSR build.
__global__ __launch_bounds__(64) void prep_count(
    const int* __restrict__ is_init, u16* __restrict__ rel16, u32* __restrict__ counts)
{
    const int n = threadIdx.x;        // 64 threads, 1 block
    const int g = n >> 4;
    int prev = 0;
    for (int t = 0; t < T_; ++t) {
        const int rel = (is_init[n * T_ + t] != 0) ? 0 : (prev + 1);
        rel16[n * T_ + t] = (u16)rel;
        atomicAdd(&counts[g * 258 + rel], 1u);
        prev = rel;
    }
}

__global__ __launch_bounds__(64) void prep_offs(
    const u32* __restrict__ counts, u32* __restrict__ offs, u32* __restrict__ cur)
{
    const int g = threadIdx.x;
    if (g < 4) {
        u32 acc = 0;
        for (int s = 0; s <= 257; ++s) {
            offs[g * 258 + s] = acc;
            cur[g * 258 + s] = acc;
            if (s < 257) acc += counts[g * 258 + s];
        }
    }
}

__global__ __launch_bounds__(64) void prep_scatter(
    const u16* __restrict__ rel16, u32* __restrict__ cur, u16* __restrict__ entries)
{
    const int n = threadIdx.x;
    const int g = n >> 4;
    for (int t = 0; t < T_; ++t) {
        const int rel = rel16[n * T_ + t];
        const u32 slot = atomicAdd(&cur[g * 258 + rel], 1u);
        entries[g * 4096 + slot] = (u16)((t << 6) | n);
    }
}

// ---------------- x-gate precompute: 256x256-tile GEMM [proven r11] ----------
__global__ __launch_bounds__(512) __attribute__((amdgpu_waves_per_eu(2, 2)))
void xgates_mfma(
    const u16* __restrict__ x_tb,   // [16384][512]
    const u16* __restrict__ Wp,     // [4096][1536] (x-part = first 512)
    const float* __restrict__ bp,   // [4096]
    u16* __restrict__ Xg)           // [16384][4096]
{
    __shared__ u16 bls[2][8192];    // 2 x 16KB, lane-major per 16-col tile
    const int bx = blockIdx.x, by = blockIdx.y;
    const int tid = threadIdx.x;
    const int v = tid >> 6, l = tid & 63;
    const int l15 = l & 15, lh = l >> 4;
    const int rowb = bx * 256 + v * 32;
    const int colb = by * 256;

    const u16* ap0 = x_tb + (size_t)(rowb + l15) * I_ + lh * 8;
    const u16* ap1 = x_tb + (size_t)(rowb + 16 + l15) * I_ + lh * 8;
    const u16* bs0 = Wp + (size_t)(colb + (2 * v) * 16 + l15) * 1536 + lh * 8;
    const u16* bs1 = Wp + (size_t)(colb + (2 * v + 1) * 16 + l15) * 1536 + lh * 8;

    f32x4 acc[2][16];
    #pragma unroll
    for (int m = 0; m < 2; ++m)
        #pragma unroll
        for (int nt = 0; nt < 16; ++nt) acc[m][nt] = f32x4{0.f, 0.f, 0.f, 0.f};

#define STAGEX(S, B) do { \
    gload_lds16n(bs0 + (S) * 32, (char*)bls[B] + (2 * v) * 1024); \
    gload_lds16n(bs1 + (S) * 32, (char*)bls[B] + (2 * v + 1) * 1024); } while (0)

    STAGEX(0, 0);
    VMW(0); __syncthreads();
    int buf = 0;
    for (int s = 0; s < 16; ++s) {
        if (s < 15) STAGEX(s + 1, buf ^ 1);
        bf16x8 a0 = *(const bf16x8*)(ap0 + s * 32);
        bf16x8 a1 = *(const bf16x8*)(ap1 + s * 32);
        const char* bb = (const char*)bls[buf];
        #pragma unroll
        for (int nt = 0; nt < 16; ++nt) {
            bf16x8 bfr = *(const bf16x8*)(bb + nt * 1024 + l * 16);
            acc[0][nt] = __builtin_amdgcn_mfma_f32_16x16x32_bf16(a0, bfr, acc[0][nt], 0, 0, 0);
            acc[1][nt] = __builtin_amdgcn_mfma_f32_16x16x32_bf16(a1, bfr, acc[1][nt], 0, 0, 0);
        }
        VMW(0); __syncthreads();
        buf ^= 1;
    }
#undef STAGEX

    #pragma unroll
    for (int nt = 0; nt < 16; ++nt) {
        const int col = colb + nt * 16 + l15;
        const float bo = bp[col];
        #pragma unroll
        for (int mt = 0; mt < 2; ++mt)
            #pragma unroll
            for (int rg = 0; rg < 4; ++rg) {
                const int row = rowb + mt * 16 + lh * 4 + rg;
                Xg[(size_t)row * 4096 + col] = f2bf(acc[mt][nt][rg] + bo);
            }
    }
}

// ---------------- segment-parallel LSTM (replaces the 256-step scan) ---------
// 256 WGs x 256 thr (4 waves). WG(u = bid&63, g = bid>>6): units u*16..+15
// (packed rows u*64..+63, weights in 128KB LDS — r13-proven preload), batch
// group g (batches g*16..+15). Iteration s processes all rows (n,t) with
// rel==s: gates = Xg + Wh·h[n,t-1]; rows with rel==0 are pure elementwise
// (h_prev=c_prev=0). Within segments r==1 (no reset factors needed).
// Sequential depth = max segment length (~15 expected; loop bound 256 exact).
// Cross-WG h/c via agent write-through stores + IC-bypass reads [proven r7+];
// per-group 64-flag barrier per iteration [proven r9+].
__global__ __launch_bounds__(256, 1) void lstm_seg(
    const u16* __restrict__ Xg,      // [16384][4096] bf16 (x-gates + biases)
    const u16* __restrict__ Wp,      // [4096][1536]
    const float* __restrict__ cx,    // (N,T,H) fp32
    const u16* __restrict__ hxbf,    // [64][1024] bf16
    const u16* __restrict__ entries, // [4][4096] CSR by rel
    const u32* __restrict__ offs,    // [4][258]
    u16* __restrict__ hs,            // [64][256][1024] bf16 (out2 lower)
    float* __restrict__ cA,          // [32][256][1024] f32 (out2 upper, n<32)
    float* __restrict__ cB,          // [32][256][1024] f32 (ws, n>=32)
    float* __restrict__ c_final,     // [64][1024] f32
    u32* __restrict__ flags)         // [4][64] x16-spaced
{
    __shared__ u16 wls[65536];       // 128 KB: h-part weights, per-wave lane-major
    __shared__ u16 zls[16384];       // 32 KB: gathered A-tile (16 rows x 1024 k)
    const int tid = threadIdx.x;
    const int v = tid >> 6, l = tid & 63;
    const int l15 = l & 15, lh = l >> 4;
    const int u = blockIdx.x & 63, g = blockIdx.x >> 6;
    const int rowbase = u * 64 + v * 16;

    // preload weights [r13-proven]
    {
        const u16* src = Wp + (size_t)(rowbase + l15) * 1536 + I_ + lh * 8;
        char* dst = (char*)wls + v * 32768;
        #pragma unroll
        for (int kk = 0; kk < 32; ++kk)
            gload_lds16n(src + kk * 32, dst + kk * 1024);
    }

    const int jb = u * 16 + v * 4 + lh;     // this lane's unit
    const u16* gent = entries + g * 4096;
    const u32* goff = offs + g * 258;
    u32* gflags = flags + g * 64 * 16;
    const char* wlsb = (const char*)wls + v * 32768;
    const char* zlsb = (const char*)zls;

    VMW(0);
    __syncthreads();

    // ---- s = 0: elementwise rows (h_prev = c_prev = 0), 2 units per thread
    {
        const int m0 = (int)goff[1];
        const int gtid = u * 256 + tid;       // 0..16383 within group
        for (int cell = gtid; cell < m0 * 512; cell += 64 * 256) {
            const int ri = cell >> 9, jj = cell & 511;
            const int j = jj * 2;
            const u16 e = gent[ri];
            const int t = e >> 6, n = e & 63;
            const u16* xp = Xg + ((size_t)t * 64 + n) * 4096 + 4 * j;
            const u16x4 xa = *(const u16x4*)(xp);
            const u16x4 xb = *(const u16x4*)(xp + 4);
            const float c0 = sigf(bf2f(xa[0])) * tanhfast(bf2f(xa[2]));
            const float h0 = sigf(bf2f(xa[3])) * tanhfast(c0);
            const float c1 = sigf(bf2f(xb[0])) * tanhfast(bf2f(xb[2]));
            const float h1 = sigf(bf2f(xb[3])) * tanhfast(c1);
            const size_t hrow = ((size_t)n * 256 + t) * 1024;
            __hip_atomic_store((u32*)(hs + hrow + j),
                               (u32)f2bf(h0) | ((u32)f2bf(h1) << 16),
                               __ATOMIC_RELAXED, __HIP_MEMORY_SCOPE_AGENT);
            __hip_atomic_store((u32*)c_ptr(n, t, j, cA, cB), __float_as_uint(c0),
                               __ATOMIC_RELAXED, __HIP_MEMORY_SCOPE_AGENT);
            __hip_atomic_store((u32*)c_ptr(n, t, j + 1, cA, cB), __float_as_uint(c1),
                               __ATOMIC_RELAXED, __HIP_MEMORY_SCOPE_AGENT);
            if (t == T_ - 1) {
                c_final[n * H_ + j] = c0;
                c_final[n * H_ + j + 1] = c1;
            }
        }
    }
    VMW(0);
    __syncthreads();
    if (tid == 0)
        __hip_atomic_store(gflags + u * 16, 1u,
                           __ATOMIC_RELAXED, __HIP_MEMORY_SCOPE_AGENT);
    if (tid < 64) {
        while (__hip_atomic_load(gflags + tid * 16, __ATOMIC_RELAXED,
                                 __HIP_MEMORY_SCOPE_AGENT) < 1u)
            __builtin_amdgcn_s_sleep(1);
    }
    __syncthreads();

    // ---- iterations s = 1.. (exact bound: rows with rel >= s exist)
    for (int s = 1; s <= 256; ++s) {
        if (goff[s] >= 4096u) break;
        const int base = (int)goff[s];
        const int last = (int)goff[s + 1] - 1;
        const int m = last + 1 - base;

        for (int mt = 0; mt * 16 < m; ++mt) {
            const int ridx = base + mt * 16 + l15;
            const int cridx = (ridx <= last) ? ridx : last;
            const bool valid = (ridx <= last);
            const u16 e = gent[cridx];
            const int t = e >> 6, n = e & 63;

            // gather-stage A-tile: 16 rows x 1024 k, per-lane global src
            const u16* rowsrc = (t == 0) ? (hxbf + n * 1024)
                                         : (hs + ((size_t)n * 256 + (t - 1)) * 1024);
            const char* lanesrc = (const char*)rowsrc + lh * 16;
            char* db = (char*)zls;
            #pragma unroll
            for (int i = 0; i < 8; ++i) {
                const int kk = v * 8 + i;
                gload_lds16_bypass(lanesrc + kk * 64, db + kk * 1024);
            }

            // per-lane epilogue operands (issued under staging latency)
            const u16x4 xg = *(const u16x4*)(Xg + ((size_t)t * 64 + n) * 4096 + 4 * jb);
            const float* cp = (t == 0) ? (cx + (size_t)n * T_ * H_ + jb)
                                       : c_ptr(n, t - 1, jb, cA, cB);
            float cprev;
            asm volatile("global_load_dword %0, %1, off sc0 sc1\n\t"
                         "s_waitcnt vmcnt(0)"
                         : "=v"(cprev) : "v"(cp) : "memory");
            __builtin_amdgcn_sched_barrier(0);
            __syncthreads();

            // MFMA: 16 packed gate-rows (wave) x 16 m-rows, K=1024
            f32x4 acc = {0.f, 0.f, 0.f, 0.f};
            #pragma unroll
            for (int kk = 0; kk < 32; ++kk) {
                bf16x8 wf = *(const bf16x8*)(wlsb + kk * 1024 + l * 16);
                bf16x8 bz = *(const bf16x8*)(zlsb + kk * 1024 + l * 16);
                acc = __builtin_amdgcn_mfma_f32_16x16x32_bf16(wf, bz, acc, 0, 0, 0);
            }

            // epilogue: lane = (unit jb, m-row l15); gates i,f,g,o
            const float ig = acc[0] + bf2f(xg[0]);
            const float fg = acc[1] + bf2f(xg[1]);
            const float gg = acc[2] + bf2f(xg[2]);
            const float og = acc[3] + bf2f(xg[3]);
            const float cn = sigf(fg) * cprev + sigf(ig) * tanhfast(gg);
            const float hv = sigf(og) * tanhfast(cn);

            const float hvp = __shfl_down(hv, 16);
            if (valid && !(lh & 1)) {
                __hip_atomic_store((u32*)(hs + ((size_t)n * 256 + t) * 1024 + jb),
                                   (u32)f2bf(hv) | ((u32)f2bf(hvp) << 16),
                                   __ATOMIC_RELAXED, __HIP_MEMORY_SCOPE_AGENT);
            }
            if (valid) {
                __hip_atomic_store((u32*)c_ptr(n, t, jb, cA, cB), __float_as_uint(cn),
                                   __ATOMIC_RELAXED, __HIP_MEMORY_SCOPE_AGENT);
                if (t == T_ - 1) c_final[n * H_ + jb] = cn;
            }
            __syncthreads();   // protect zls before next tile's staging
        }

        // group barrier: phase s complete
        VMW(0);
        __syncthreads();
        if (tid == 0)
            __hip_atomic_store(gflags + u * 16, (u32)(s + 1),
                               __ATOMIC_RELAXED, __HIP_MEMORY_SCOPE_AGENT);
        if (tid < 64) {
            while (__hip_atomic_load(gflags + tid * 16, __ATOMIC_RELAXED,
                                     __HIP_MEMORY_SCOPE_AGENT) < (u32)(s + 1))
                __builtin_amdgcn_s_sleep(1);
        }
        __syncthreads();
    }
}

// ---------------- output projection: 256x256-tile GEMM + mish [proven r11] ---
__global__ __launch_bounds__(512) __attribute__((amdgpu_waves_per_eu(2, 2)))
void out_proj_mfma(
    const u16* __restrict__ hs,     // [16384][1024]
    const u16* __restrict__ Wo,     // [1024][1024]
    const float* __restrict__ b_out,
    float* __restrict__ out0)       // [16384][1024]
{
    __shared__ u16 bls[2][8192];    // 2 x 16KB
    const int bx = blockIdx.x, by = blockIdx.y;
    const int tid = threadIdx.x;
    const int v = tid >> 6, l = tid & 63;
    const int l15 = l & 15, lh = l >> 4;
    const int rowb = bx * 256 + v * 32;
    const int colb = by * 256;

    const u16* ap0 = hs + (size_t)(rowb + l15) * H_ + lh * 8;
    const u16* ap1 = hs + (size_t)(rowb + 16 + l15) * H_ + lh * 8;
    const u16* bs0 = Wo + (size_t)(colb + (2 * v) * 16 + l15) * H_ + lh * 8;
    const u16* bs1 = Wo + (size_t)(colb + (2 * v + 1) * 16 + l15) * H_ + lh * 8;

    f32x4 acc[2][16];
    #pragma unroll
    for (int m = 0; m < 2; ++m)
        #pragma unroll
        for (int nt = 0; nt < 16; ++nt) acc[m][nt] = f32x4{0.f, 0.f, 0.f, 0.f};

#define STAGEO(S, B) do { \
    gload_lds16n(bs0 + (S) * 32, (char*)bls[B] + (2 * v) * 1024); \
    gload_lds16n(bs1 + (S) * 32, (char*)bls[B] + (2 * v + 1) * 1024); } while (0)

    STAGEO(0, 0);
    VMW(0); __syncthreads();
    int buf = 0;
    for (int s = 0; s < 32; ++s) {
        if (s < 31) STAGEO(s + 1, buf ^ 1);
        bf16x8 a0 = *(const bf16x8*)(ap0 + s * 32);
        bf16x8 a1 = *(const bf16x8*)(ap1 + s * 32);
        const char* bb = (const char*)bls[buf];
        #pragma unroll
        for (int nt = 0; nt < 16; ++nt) {
            bf16x8 bfr = *(const bf16x8*)(bb + nt * 1024 + l * 16);
            acc[0][nt] = __builtin_amdgcn_mfma_f32_16x16x32_bf16(a0, bfr, acc[0][nt], 0, 0, 0);
            acc[1][nt] = __builtin_amdgcn_mfma_f32_16x16x32_bf16(a1, bfr, acc[1][nt], 0, 0, 0);
        }
        VMW(0); __syncthreads();
        buf ^= 1;
    }
#undef STAGEO

    #pragma unroll
    for (int nt = 0; nt < 16; ++nt) {
        const int col = colb + nt * 16 + l15;
        const float bo = b_out[col];
        #pragma unroll
        for (int mt = 0; mt < 2; ++mt)
            #pragma unroll
            for (int rg = 0; rg < 4; ++rg) {
                const int row = rowb + mt * 16 + lh * 4 + rg;
                const float y = acc[mt][nt][rg] + bo;
                const float sp = (y > 15.f) ? y : log1pf(__expf(y));
                out0[(size_t)row * H_ + col] = y * tanhfast(sp);
            }
    }
}

// out1 = broadcast hs[:,255,:]  (hs in out2 region — MUST run before bcast_c)
__global__ __launch_bounds__(256) void bcast_h(
    const u16* __restrict__ hs, float* __restrict__ out1)
{
    const size_t total = (size_t)N_ * T_ * H_;
    for (size_t idx = (size_t)blockIdx.x * 256 + threadIdx.x; idx < total;
         idx += (size_t)gridDim.x * 256) {
        const int n = (int)(idx >> 18);
        const int j = (int)(idx & (H_ - 1));
        out1[idx] = bf2f(hs[((size_t)n * T_ + (T_ - 1)) * H_ + j]);
    }
}

__global__ __launch_bounds__(256) void bcast_c(
    const float* __restrict__ c_final, float* __restrict__ out2)
{
    const size_t total = (size_t)N_ * T_ * H_;
    for (size_t idx = (size_t)blockIdx.x * 256 + threadIdx.x; idx < total;
         idx += (size_t)gridDim.x * 256) {
        const int n = (int)(idx >> 18);
        const int j = (int)(idx & (H_ - 1));
        out2[idx] = c_final[n * H_ + j];
    }
}

extern "C" void kernel_launch(void* const* d_in, const int* in_sizes, int n_in,
                              void* d_out, int out_size, void* d_ws, size_t ws_size,
                              hipStream_t stream) {
    const float* x      = (const float*)d_in[0];
    const int*   is_ini = (const int*)  d_in[1];
    const float* hx     = (const float*)d_in[2];
    const float* cx     = (const float*)d_in[3];
    const float* W_ih   = (const float*)d_in[4];
    const float* W_hh   = (const float*)d_in[5];
    const float* b_ih   = (const float*)d_in[6];
    const float* b_hh   = (const float*)d_in[7];
    const float* W_out  = (const float*)d_in[8];
    const float* b_out  = (const float*)d_in[9];

    float* out0 = (float*)d_out;
    float* out1 = out0 + (size_t)N_ * T_ * H_;
    float* out2 = out1 + (size_t)N_ * T_ * H_;

    char* ws = (char*)d_ws;
    u16*   x_tb    = (u16*)  (ws + 0);          // 16,777,216
    u16*   Wp      = (u16*)  (ws + 16777216);   // 12,582,912
    float* bp      = (float*)(ws + 29360128);   // 16,384
    u16*   Wo_b    = (u16*)  (ws + 29376512);   // 2,097,152
    float* c_final = (float*)(ws + 31473664);   // 262,144
    u16*   hxbf    = (u16*)  (ws + 31735808);   // 131,072
    u16*   rel16   = (u16*)  (ws + 31866880);   // 32,768
    u16*   entries = (u16*)  (ws + 31899648);   // 32,768
    u32*   offs    = (u32*)  (ws + 31932416);   // 4,352 (pad)
    u32*   cur     = (u32*)  (ws + 31936768);   // 4,352
    u32*   counts  = (u32*)  (ws + 31941120);   // 4,352
    u32*   flags   = (u32*)  (ws + 31945472);   // 16,384   [4][64] x16-spaced
    float* cB      = (float*)(ws + 31961856);   // 33,554,432 (c for n>=32)
                                                // ws end ~65.5 MB (r2-proven size)

    u16*   Xg = (u16*)out0;             // 134.2 MB scratch (out0+out1), consumed
    u16*   hs = (u16*)out2;             // 33.55 MB (out2 lower half)
    float* cA = (float*)(out2 + (size_t)32 * 256 * 1024);  // out2 upper (n<32)

    hipMemsetAsync(counts, 0, 4352 + 16384, stream);  // counts + flags (adjacent)
    pack_weights<<<4096, 256, 0, stream>>>(W_ih, W_hh, b_ih, b_hh, Wp, bp);
    conv_x<<<dim3(T_, N_), 256, 0, stream>>>(x, x_tb);
    conv_wout<<<1024, 256, 0, stream>>>(W_out, Wo_b);
    conv_hx<<<256, 256, 0, stream>>>(hx, hxbf);
    prep_count<<<1, 64, 0, stream>>>(is_ini, rel16, counts);
    prep_offs<<<1, 64, 0, stream>>>(counts, offs, cur);
    prep_scatter<<<1, 64, 0, stream>>>(rel16, cur, entries);

    xgates_mfma<<<dim3(64, 16), 512, 0, stream>>>(x_tb, Wp, bp, Xg);

    lstm_seg<<<256, 256, 0, stream>>>(Xg, Wp, cx, hxbf, entries, offs,
                                      hs, cA, cB, c_final, flags);

    out_proj_mfma<<<dim3(64, 4), 512, 0, stream>>>(hs, Wo_b, b_out, out0);
    bcast_h<<<2048, 256, 0, stream>>>(hs, out1);
    bcast_c<<<2048, 256, 0, stream>>>(c_final, out2);
}

// Round 15
// 1187.457 us; speedup vs baseline: 1.2695x; 1.0834x over previous
//
#include <hip/hip_runtime.h>
#include <math.h>

#define N_ 64
#define T_ 256
#define I_ 512
#define H_ 1024

typedef unsigned short u16;
typedef unsigned int u32;
typedef unsigned long long u64;
typedef short bf16x8 __attribute__((ext_vector_type(8)));
typedef float f32x4 __attribute__((ext_vector_type(4)));
typedef u16 u16x4 __attribute__((ext_vector_type(4)));
typedef u64 u64x2 __attribute__((ext_vector_type(2)));

__device__ __forceinline__ u16 f2bf(float f) {
    union { float f; unsigned int u; } x; x.f = f;
    unsigned int r = (x.u + 0x7FFFu + ((x.u >> 16) & 1u)) >> 16;
    return (u16)r;
}
__device__ __forceinline__ float bf2f(u16 u) {
    union { unsigned int u; float f; } x; x.u = ((unsigned int)u) << 16;
    return x.f;
}
__device__ __forceinline__ float sigf(float v) {
    return 1.0f / (1.0f + __expf(-v));
}
__device__ __forceinline__ float tanhfast(float x) {
    float e = __expf(2.0f * x);
    return 1.0f - 2.0f / (e + 1.0f);   // NaN-free at +-inf
}

// cached global->LDS (weight staging)
__device__ __forceinline__ void gload_lds16n(const void* g, void* l) {
    __builtin_amdgcn_global_load_lds(
        (__attribute__((address_space(1))) void*)(g),
        (__attribute__((address_space(3))) void*)(l), 16, 0, 0);
}

#define VMW(Ncnt) do { \
    asm volatile("s_waitcnt vmcnt(" #Ncnt ")" ::: "memory"); \
    __builtin_amdgcn_sched_barrier(0); } while (0)

// c storage split: n<32 -> cA (upper half of out2), n>=32 -> cB (ws)
__device__ __forceinline__ float* c_ptr(int n, int t, int j, float* cA, float* cB) {
    return (n < 32) ? (cA + (((size_t)(n * 256 + t)) << 10) + j)
                    : (cB + (((size_t)((n - 32) * 256 + t)) << 10) + j);
}

// ---------------- prep kernels ----------------

// Packed row rp = j*4+g : [W_ih[g*H+j][0:512] ; W_hh[g*H+j][0:1024]] bf16
__global__ __launch_bounds__(256) void pack_weights(
    const float* __restrict__ W_ih, const float* __restrict__ W_hh,
    const float* __restrict__ b_ih, const float* __restrict__ b_hh,
    u16* __restrict__ Wp, float* __restrict__ bp)
{
    const int rp = blockIdx.x;            // 0..4095
    const int j = rp >> 2, g = rp & 3;
    const int src = g * H_ + j;
    const float* wi = W_ih + (size_t)src * I_;
    const float* wh = W_hh + (size_t)src * H_;
    u16* dst = Wp + (size_t)rp * (I_ + H_);
    for (int k = threadIdx.x; k < I_; k += 256) dst[k] = f2bf(wi[k]);
    for (int k = threadIdx.x; k < H_; k += 256) dst[I_ + k] = f2bf(wh[k]);
    if (threadIdx.x == 0) bp[rp] = b_ih[src] + b_hh[src];
}

__global__ __launch_bounds__(256) void conv_x(
    const float* __restrict__ x, u16* __restrict__ x_tb)
{
    const int t = blockIdx.x, n = blockIdx.y;
    const float* s = x + ((size_t)n * T_ + t) * I_;
    u16* d = x_tb + ((size_t)t * N_ + n) * I_;
    for (int k = threadIdx.x; k < I_; k += 256) d[k] = f2bf(s[k]);
}

__global__ __launch_bounds__(256) void conv_wout(
    const float* __restrict__ W, u16* __restrict__ Wb)
{
    const size_t base = (size_t)blockIdx.x * 1024 + threadIdx.x;
    #pragma unroll
    for (int q = 0; q < 4; ++q) Wb[base + q * 256] = f2bf(W[base + q * 256]);
}

// hxbf[n][j] = bf16(hx[n,0,j])   (UNscaled; only read by rows with r=1)
__global__ __launch_bounds__(256) void conv_hx(
    const float* __restrict__ hx, u16* __restrict__ hxbf)
{
    const int idx = blockIdx.x * 256 + threadIdx.x;   // 65536
    const int n = idx >> 10, j = idx & (H_ - 1);
    hxbf[idx] = f2bf(hx[(size_t)n * T_ * H_ + j]);
}

// rel[n,t] = 0 if is_init, else distance to previous reset (t+1 if none).
// Parallel: 64 WGs (one per n) x 256 threads (one per t), backward scan in LDS.
__global__ __launch_bounds__(256) void prep_rel(
    const int* __restrict__ is_init, u16* __restrict__ rel16)
{
    __shared__ u16 ii[256];
    const int n = blockIdx.x, t = threadIdx.x;
    ii[t] = (u16)(is_init[n * T_ + t] != 0);
    __syncthreads();
    int rel = t + 1;
    for (int d = 0; d <= t; ++d) {
        if (ii[t - d]) { rel = d; break; }
    }
    rel16[n * T_ + t] = (u16)rel;
}

// Per batch-group: LDS histogram of rel -> exclusive offsets -> scatter CSR.
__global__ __launch_bounds__(256) void prep_bucket(
    const u16* __restrict__ rel16, u16* __restrict__ entries, u32* __restrict__ offs)
{
    __shared__ u32 hist[258];
    __shared__ u32 offsh[258];
    const int g = blockIdx.x, tid = threadIdx.x;
    for (int i = tid; i < 258; i += 256) hist[i] = 0;
    __syncthreads();
    for (int i = tid; i < 4096; i += 256) {
        const int n = g * 16 + (i & 15), t = i >> 4;
        atomicAdd(&hist[rel16[n * T_ + t]], 1u);
    }
    __syncthreads();
    if (tid == 0) {
        u32 acc = 0;
        for (int s = 0; s < 258; ++s) { offsh[s] = acc; acc += hist[s]; }
    }
    __syncthreads();
    for (int i = tid; i < 258; i += 256) {
        offs[g * 258 + i] = offsh[i];
        hist[i] = offsh[i];          // reuse as scatter cursor
    }
    __syncthreads();
    for (int i = tid; i < 4096; i += 256) {
        const int n = g * 16 + (i & 15), t = i >> 4;
        const int rel = rel16[n * T_ + t];
        const u32 slot = atomicAdd(&hist[rel], 1u);
        entries[g * 4096 + slot] = (u16)((t << 6) | n);
    }
}

// ---------------- x-gate precompute: 256x256-tile GEMM [proven r11] ----------
__global__ __launch_bounds__(512) __attribute__((amdgpu_waves_per_eu(2, 2)))
void xgates_mfma(
    const u16* __restrict__ x_tb,   // [16384][512]
    const u16* __restrict__ Wp,     // [4096][1536] (x-part = first 512)
    const float* __restrict__ bp,   // [4096]
    u16* __restrict__ Xg)           // [16384][4096]
{
    __shared__ u16 bls[2][8192];    // 2 x 16KB, lane-major per 16-col tile
    const int bx = blockIdx.x, by = blockIdx.y;
    const int tid = threadIdx.x;
    const int v = tid >> 6, l = tid & 63;
    const int l15 = l & 15, lh = l >> 4;
    const int rowb = bx * 256 + v * 32;
    const int colb = by * 256;

    const u16* ap0 = x_tb + (size_t)(rowb + l15) * I_ + lh * 8;
    const u16* ap1 = x_tb + (size_t)(rowb + 16 + l15) * I_ + lh * 8;
    const u16* bs0 = Wp + (size_t)(colb + (2 * v) * 16 + l15) * 1536 + lh * 8;
    const u16* bs1 = Wp + (size_t)(colb + (2 * v + 1) * 16 + l15) * 1536 + lh * 8;

    f32x4 acc[2][16];
    #pragma unroll
    for (int m = 0; m < 2; ++m)
        #pragma unroll
        for (int nt = 0; nt < 16; ++nt) acc[m][nt] = f32x4{0.f, 0.f, 0.f, 0.f};

#define STAGEX(S, B) do { \
    gload_lds16n(bs0 + (S) * 32, (char*)bls[B] + (2 * v) * 1024); \
    gload_lds16n(bs1 + (S) * 32, (char*)bls[B] + (2 * v + 1) * 1024); } while (0)

    STAGEX(0, 0);
    VMW(0); __syncthreads();
    int buf = 0;
    for (int s = 0; s < 16; ++s) {
        if (s < 15) STAGEX(s + 1, buf ^ 1);
        bf16x8 a0 = *(const bf16x8*)(ap0 + s * 32);
        bf16x8 a1 = *(const bf16x8*)(ap1 + s * 32);
        const char* bb = (const char*)bls[buf];
        #pragma unroll
        for (int nt = 0; nt < 16; ++nt) {
            bf16x8 bfr = *(const bf16x8*)(bb + nt * 1024 + l * 16);
            acc[0][nt] = __builtin_amdgcn_mfma_f32_16x16x32_bf16(a0, bfr, acc[0][nt], 0, 0, 0);
            acc[1][nt] = __builtin_amdgcn_mfma_f32_16x16x32_bf16(a1, bfr, acc[1][nt], 0, 0, 0);
        }
        VMW(0); __syncthreads();
        buf ^= 1;
    }
#undef STAGEX

    #pragma unroll
    for (int nt = 0; nt < 16; ++nt) {
        const int col = colb + nt * 16 + l15;
        const float bo = bp[col];
        #pragma unroll
        for (int mt = 0; mt < 2; ++mt)
            #pragma unroll
            for (int rg = 0; rg < 4; ++rg) {
                const int row = rowb + mt * 16 + lh * 4 + rg;
                Xg[(size_t)row * 4096 + col] = f2bf(acc[mt][nt][rg] + bo);
            }
    }
}

// ---------------- segment-parallel LSTM, software-pipelined tiles ------------
// [r14 structure] + per-tile register prefetch: tile mt+1's h rows / c / xg are
// loaded (agent-scope atomic loads, IC-coherent, compiler-managed waits) while
// tile mt runs ds_write -> MFMA -> epilogue. Removes the exposed per-tile IC
// round trip that made r14's tiles ~2us.
__global__ __launch_bounds__(256, 1) void lstm_seg(
    const u16* __restrict__ Xg,      // [16384][4096] bf16 (x-gates + biases)
    const u16* __restrict__ Wp,      // [4096][1536]
    const float* __restrict__ cx,    // (N,T,H) fp32
    const u16* __restrict__ hxbf,    // [64][1024] bf16
    const u16* __restrict__ entries, // [4][4096] CSR by rel
    const u32* __restrict__ offs,    // [4][258]
    u16* __restrict__ hs,            // [64][256][1024] bf16 (out2 lower)
    float* __restrict__ cA,          // [32][256][1024] f32 (out2 upper, n<32)
    float* __restrict__ cB,          // [32][256][1024] f32 (ws, n>=32)
    float* __restrict__ c_final,     // [64][1024] f32
    u32* __restrict__ flags)         // [4][64] x16-spaced
{
    __shared__ u16 wls[65536];       // 128 KB: h-part weights, per-wave lane-major
    __shared__ u16 zls[16384];       // 32 KB: gathered A-tile (16 rows x 1024 k)
    const int tid = threadIdx.x;
    const int v = tid >> 6, l = tid & 63;
    const int l15 = l & 15, lh = l >> 4;
    const int u = blockIdx.x & 63, g = blockIdx.x >> 6;
    const int rowbase = u * 64 + v * 16;

    // preload weights [r13-proven]
    {
        const u16* src = Wp + (size_t)(rowbase + l15) * 1536 + I_ + lh * 8;
        char* dst = (char*)wls + v * 32768;
        #pragma unroll
        for (int kk = 0; kk < 32; ++kk)
            gload_lds16n(src + kk * 32, dst + kk * 1024);
    }

    const int jb = u * 16 + v * 4 + lh;     // this lane's unit
    const u16* gent = entries + g * 4096;
    const u32* goff = offs + g * 258;
    u32* gflags = flags + g * 64 * 16;
    const char* wlsb = (const char*)wls + v * 32768;
    const char* zlsb = (const char*)zls;
    char* zlsw = (char*)zls;

    VMW(0);
    __syncthreads();

    // ---- s = 0: elementwise rows (h_prev = c_prev = 0), 2 units per thread
    {
        const int m0 = (int)goff[1];
        const int gtid = u * 256 + tid;       // 0..16383 within group
        for (int cell = gtid; cell < m0 * 512; cell += 64 * 256) {
            const int ri = cell >> 9, jj = cell & 511;
            const int j = jj * 2;
            const u16 e = gent[ri];
            const int t = e >> 6, n = e & 63;
            const u16* xp = Xg + ((size_t)t * 64 + n) * 4096 + 4 * j;
            const u16x4 xa = *(const u16x4*)(xp);
            const u16x4 xb = *(const u16x4*)(xp + 4);
            const float c0 = sigf(bf2f(xa[0])) * tanhfast(bf2f(xa[2]));
            const float h0 = sigf(bf2f(xa[3])) * tanhfast(c0);
            const float c1 = sigf(bf2f(xb[0])) * tanhfast(bf2f(xb[2]));
            const float h1 = sigf(bf2f(xb[3])) * tanhfast(c1);
            const size_t hrow = ((size_t)n * 256 + t) * 1024;
            __hip_atomic_store((u32*)(hs + hrow + j),
                               (u32)f2bf(h0) | ((u32)f2bf(h1) << 16),
                               __ATOMIC_RELAXED, __HIP_MEMORY_SCOPE_AGENT);
            __hip_atomic_store((u32*)c_ptr(n, t, j, cA, cB), __float_as_uint(c0),
                               __ATOMIC_RELAXED, __HIP_MEMORY_SCOPE_AGENT);
            __hip_atomic_store((u32*)c_ptr(n, t, j + 1, cA, cB), __float_as_uint(c1),
                               __ATOMIC_RELAXED, __HIP_MEMORY_SCOPE_AGENT);
            if (t == T_ - 1) {
                c_final[n * H_ + j] = c0;
                c_final[n * H_ + j + 1] = c1;
            }
        }
    }
    VMW(0);
    __syncthreads();
    if (tid == 0)
        __hip_atomic_store(gflags + u * 16, 1u,
                           __ATOMIC_RELAXED, __HIP_MEMORY_SCOPE_AGENT);
    if (tid < 64) {
        while (__hip_atomic_load(gflags + tid * 16, __ATOMIC_RELAXED,
                                 __HIP_MEMORY_SCOPE_AGENT) < 1u)
            __builtin_amdgcn_s_sleep(1);
    }
    __syncthreads();
    __builtin_amdgcn_sched_barrier(0);

    // prefetch state (next tile): 8 chunks x 16B + c + xg + meta
    u64 rb[16];
    int nt_t = 0, nt_n = 0; bool nt_valid = false;
    float nc = 0.f; u16x4 nxg = u16x4{0, 0, 0, 0};

#define LOADT(MT, BASE, LAST) do { \
    const int ridx_ = (BASE) + (MT) * 16 + l15; \
    nt_valid = (ridx_ <= (LAST)); \
    const int cr_ = nt_valid ? ridx_ : (LAST); \
    const u16 e_ = gent[cr_]; \
    nt_t = e_ >> 6; nt_n = e_ & 63; \
    const u16* rowsrc_ = (nt_t == 0) ? (hxbf + nt_n * 1024) \
                       : (hs + ((size_t)nt_n * 256 + (nt_t - 1)) * 1024); \
    const char* lsrc_ = (const char*)rowsrc_ + lh * 16; \
    _Pragma("unroll") \
    for (int i_ = 0; i_ < 8; ++i_) { \
        const char* a_ = lsrc_ + (v * 8 + i_) * 64; \
        rb[2 * i_]     = __hip_atomic_load((const u64*)a_, \
                             __ATOMIC_RELAXED, __HIP_MEMORY_SCOPE_AGENT); \
        rb[2 * i_ + 1] = __hip_atomic_load((const u64*)(a_ + 8), \
                             __ATOMIC_RELAXED, __HIP_MEMORY_SCOPE_AGENT); \
    } \
    const float* cp_ = (nt_t == 0) ? (cx + (size_t)nt_n * T_ * H_ + jb) \
                                   : c_ptr(nt_n, nt_t - 1, jb, cA, cB); \
    nc = __uint_as_float(__hip_atomic_load((const u32*)cp_, \
                             __ATOMIC_RELAXED, __HIP_MEMORY_SCOPE_AGENT)); \
    nxg = *(const u16x4*)(Xg + ((size_t)nt_t * 64 + nt_n) * 4096 + 4 * jb); \
} while (0)

    // ---- iterations s = 1.. (exact bound: rows with rel >= s exist)
    for (int s = 1; s <= 256; ++s) {
        if (goff[s] >= 4096u) break;
        const int base = (int)goff[s];
        const int last = (int)goff[s + 1] - 1;
        const int ntiles = ((last + 1 - base) + 15) >> 4;

        LOADT(0, base, last);
        for (int mt = 0; mt < ntiles; ++mt) {
            const int cu_t = nt_t, cu_n = nt_n;
            const bool cu_valid = nt_valid;
            const float cu_c = nc;
            const u16x4 cu_xg = nxg;

            __syncthreads();          // zls free (all waves done prev MFMA)
            #pragma unroll
            for (int i = 0; i < 8; ++i) {
                u64x2 w; w.x = rb[2 * i]; w.y = rb[2 * i + 1];
                *(u64x2*)(zlsw + (v * 8 + i) * 1024 + l * 16) = w;
            }
            if (mt + 1 < ntiles) LOADT(mt + 1, base, last);
            __syncthreads();          // zls ready

            f32x4 acc = {0.f, 0.f, 0.f, 0.f};
            #pragma unroll
            for (int kk = 0; kk < 32; ++kk) {
                bf16x8 wf = *(const bf16x8*)(wlsb + kk * 1024 + l * 16);
                bf16x8 bz = *(const bf16x8*)(zlsb + kk * 1024 + l * 16);
                acc = __builtin_amdgcn_mfma_f32_16x16x32_bf16(wf, bz, acc, 0, 0, 0);
            }

            // epilogue: lane = (unit jb, m-row l15); gates i,f,g,o
            const float ig = acc[0] + bf2f(cu_xg[0]);
            const float fg = acc[1] + bf2f(cu_xg[1]);
            const float gg = acc[2] + bf2f(cu_xg[2]);
            const float og = acc[3] + bf2f(cu_xg[3]);
            const float cn = sigf(fg) * cu_c + sigf(ig) * tanhfast(gg);
            const float hv = sigf(og) * tanhfast(cn);

            const float hvp = __shfl_down(hv, 16);
            if (cu_valid && !(lh & 1)) {
                __hip_atomic_store((u32*)(hs + ((size_t)cu_n * 256 + cu_t) * 1024 + jb),
                                   (u32)f2bf(hv) | ((u32)f2bf(hvp) << 16),
                                   __ATOMIC_RELAXED, __HIP_MEMORY_SCOPE_AGENT);
            }
            if (cu_valid) {
                __hip_atomic_store((u32*)c_ptr(cu_n, cu_t, jb, cA, cB),
                                   __float_as_uint(cn),
                                   __ATOMIC_RELAXED, __HIP_MEMORY_SCOPE_AGENT);
                if (cu_t == T_ - 1) c_final[cu_n * H_ + jb] = cn;
            }
        }

        // group barrier: phase s complete
        VMW(0);
        __syncthreads();
        if (tid == 0)
            __hip_atomic_store(gflags + u * 16, (u32)(s + 1),
                               __ATOMIC_RELAXED, __HIP_MEMORY_SCOPE_AGENT);
        if (tid < 64) {
            while (__hip_atomic_load(gflags + tid * 16, __ATOMIC_RELAXED,
                                     __HIP_MEMORY_SCOPE_AGENT) < (u32)(s + 1))
                __builtin_amdgcn_s_sleep(1);
        }
        __syncthreads();
        __builtin_amdgcn_sched_barrier(0);
    }
#undef LOADT
}

// ---------------- output projection: 256x256-tile GEMM + mish [proven r11] ---
__global__ __launch_bounds__(512) __attribute__((amdgpu_waves_per_eu(2, 2)))
void out_proj_mfma(
    const u16* __restrict__ hs,     // [16384][1024]
    const u16* __restrict__ Wo,     // [1024][1024]
    const float* __restrict__ b_out,
    float* __restrict__ out0)       // [16384][1024]
{
    __shared__ u16 bls[2][8192];    // 2 x 16KB
    const int bx = blockIdx.x, by = blockIdx.y;
    const int tid = threadIdx.x;
    const int v = tid >> 6, l = tid & 63;
    const int l15 = l & 15, lh = l >> 4;
    const int rowb = bx * 256 + v * 32;
    const int colb = by * 256;

    const u16* ap0 = hs + (size_t)(rowb + l15) * H_ + lh * 8;
    const u16* ap1 = hs + (size_t)(rowb + 16 + l15) * H_ + lh * 8;
    const u16* bs0 = Wo + (size_t)(colb + (2 * v) * 16 + l15) * H_ + lh * 8;
    const u16* bs1 = Wo + (size_t)(colb + (2 * v + 1) * 16 + l15) * H_ + lh * 8;

    f32x4 acc[2][16];
    #pragma unroll
    for (int m = 0; m < 2; ++m)
        #pragma unroll
        for (int nt = 0; nt < 16; ++nt) acc[m][nt] = f32x4{0.f, 0.f, 0.f, 0.f};

#define STAGEO(S, B) do { \
    gload_lds16n(bs0 + (S) * 32, (char*)bls[B] + (2 * v) * 1024); \
    gload_lds16n(bs1 + (S) * 32, (char*)bls[B] + (2 * v + 1) * 1024); } while (0)

    STAGEO(0, 0);
    VMW(0); __syncthreads();
    int buf = 0;
    for (int s = 0; s < 32; ++s) {
        if (s < 31) STAGEO(s + 1, buf ^ 1);
        bf16x8 a0 = *(const bf16x8*)(ap0 + s * 32);
        bf16x8 a1 = *(const bf16x8*)(ap1 + s * 32);
        const char* bb = (const char*)bls[buf];
        #pragma unroll
        for (int nt = 0; nt < 16; ++nt) {
            bf16x8 bfr = *(const bf16x8*)(bb + nt * 1024 + l * 16);
            acc[0][nt] = __builtin_amdgcn_mfma_f32_16x16x32_bf16(a0, bfr, acc[0][nt], 0, 0, 0);
            acc[1][nt] = __builtin_amdgcn_mfma_f32_16x16x32_bf16(a1, bfr, acc[1][nt], 0, 0, 0);
        }
        VMW(0); __syncthreads();
        buf ^= 1;
    }
#undef STAGEO

    #pragma unroll
    for (int nt = 0; nt < 16; ++nt) {
        const int col = colb + nt * 16 + l15;
        const float bo = b_out[col];
        #pragma unroll
        for (int mt = 0; mt < 2; ++mt)
            #pragma unroll
            for (int rg = 0; rg < 4; ++rg) {
                const int row = rowb + mt * 16 + lh * 4 + rg;
                const float y = acc[mt][nt][rg] + bo;
                const float sp = (y > 15.f) ? y : log1pf(__expf(y));
                out0[(size_t)row * H_ + col] = y * tanhfast(sp);
            }
    }
}

// out1 = broadcast hs[:,255,:]  (hs in out2 region — MUST run before bcast_c)
__global__ __launch_bounds__(256) void bcast_h(
    const u16* __restrict__ hs, float* __restrict__ out1)
{
    const size_t total = (size_t)N_ * T_ * H_;
    for (size_t idx = (size_t)blockIdx.x * 256 + threadIdx.x; idx < total;
         idx += (size_t)gridDim.x * 256) {
        const int n = (int)(idx >> 18);
        const int j = (int)(idx & (H_ - 1));
        out1[idx] = bf2f(hs[((size_t)n * T_ + (T_ - 1)) * H_ + j]);
    }
}

__global__ __launch_bounds__(256) void bcast_c(
    const float* __restrict__ c_final, float* __restrict__ out2)
{
    const size_t total = (size_t)N_ * T_ * H_;
    for (size_t idx = (size_t)blockIdx.x * 256 + threadIdx.x; idx < total;
         idx += (size_t)gridDim.x * 256) {
        const int n = (int)(idx >> 18);
        const int j = (int)(idx & (H_ - 1));
        out2[idx] = c_final[n * H_ + j];
    }
}

extern "C" void kernel_launch(void* const* d_in, const int* in_sizes, int n_in,
                              void* d_out, int out_size, void* d_ws, size_t ws_size,
                              hipStream_t stream) {
    const float* x      = (const float*)d_in[0];
    const int*   is_ini = (const int*)  d_in[1];
    const float* hx     = (const float*)d_in[2];
    const float* cx     = (const float*)d_in[3];
    const float* W_ih   = (const float*)d_in[4];
    const float* W_hh   = (const float*)d_in[5];
    const float* b_ih   = (const float*)d_in[6];
    const float* b_hh   = (const float*)d_in[7];
    const float* W_out  = (const float*)d_in[8];
    const float* b_out  = (const float*)d_in[9];

    float* out0 = (float*)d_out;
    float* out1 = out0 + (size_t)N_ * T_ * H_;
    float* out2 = out1 + (size_t)N_ * T_ * H_;

    char* ws = (char*)d_ws;
    u16*   x_tb    = (u16*)  (ws + 0);          // 16,777,216
    u16*   Wp      = (u16*)  (ws + 16777216);   // 12,582,912
    float* bp      = (float*)(ws + 29360128);   // 16,384
    u16*   Wo_b    = (u16*)  (ws + 29376512);   // 2,097,152
    float* c_final = (float*)(ws + 31473664);   // 262,144
    u16*   hxbf    = (u16*)  (ws + 31735808);   // 131,072
    u16*   rel16   = (u16*)  (ws + 31866880);   // 32,768
    u16*   entries = (u16*)  (ws + 31899648);   // 32,768
    u32*   offs    = (u32*)  (ws + 31932416);   // 4,352 (pad)
    u32*   flags   = (u32*)  (ws + 31945472);   // 16,384   [4][64] x16-spaced
    float* cB      = (float*)(ws + 31961856);   // 33,554,432 (c for n>=32)
                                                // ws end ~65.5 MB (r2-proven size)

    u16*   Xg = (u16*)out0;             // 134.2 MB scratch (out0+out1), consumed
    u16*   hs = (u16*)out2;             // 33.55 MB (out2 lower half)
    float* cA = (float*)(out2 + (size_t)32 * 256 * 1024);  // out2 upper (n<32)

    hipMemsetAsync(flags, 0, 16384, stream);
    pack_weights<<<4096, 256, 0, stream>>>(W_ih, W_hh, b_ih, b_hh, Wp, bp);
    conv_x<<<dim3(T_, N_), 256, 0, stream>>>(x, x_tb);
    conv_wout<<<1024, 256, 0, stream>>>(W_out, Wo_b);
    conv_hx<<<256, 256, 0, stream>>>(hx, hxbf);
    prep_rel<<<64, 256, 0, stream>>>(is_ini, rel16);
    prep_bucket<<<4, 256, 0, stream>>>(rel16, entries, offs);

    xgates_mfma<<<dim3(64, 16), 512, 0, stream>>>(x_tb, Wp, bp, Xg);

    lstm_seg<<<256, 256, 0, stream>>>(Xg, Wp, cx, hxbf, entries, offs,
                                      hs, cA, cB, c_final, flags);

    out_proj_mfma<<<dim3(64, 4), 512, 0, stream>>>(hs, Wo_b, b_out, out0);
    bcast_h<<<2048, 256, 0, stream>>>(hs, out1);
    bcast_c<<<2048, 256, 0, stream>>>(c_final, out2);
}

// Round 16
// 1185.112 us; speedup vs baseline: 1.2720x; 1.0020x over previous
//
#include <hip/hip_runtime.h>
#include <math.h>

#define N_ 64
#define T_ 256
#define I_ 512
#define H_ 1024

typedef unsigned short u16;
typedef unsigned int u32;
typedef unsigned long long u64;
typedef short bf16x8 __attribute__((ext_vector_type(8)));
typedef float f32x4 __attribute__((ext_vector_type(4)));
typedef u16 u16x4 __attribute__((ext_vector_type(4)));

__device__ __forceinline__ u16 f2bf(float f) {
    union { float f; unsigned int u; } x; x.f = f;
    unsigned int r = (x.u + 0x7FFFu + ((x.u >> 16) & 1u)) >> 16;
    return (u16)r;
}
__device__ __forceinline__ float bf2f(u16 u) {
    union { unsigned int u; float f; } x; x.u = ((unsigned int)u) << 16;
    return x.f;
}
__device__ __forceinline__ float sigf(float v) {
    return 1.0f / (1.0f + __expf(-v));
}
__device__ __forceinline__ float tanhfast(float x) {
    float e = __expf(2.0f * x);
    return 1.0f - 2.0f / (e + 1.0f);   // NaN-free at +-inf
}

// cached global->LDS (weight staging)
__device__ __forceinline__ void gload_lds16n(const void* g, void* l) {
    __builtin_amdgcn_global_load_lds(
        (__attribute__((address_space(1))) void*)(g),
        (__attribute__((address_space(3))) void*)(l), 16, 0, 0);
}

#define VMW(Ncnt) do { \
    asm volatile("s_waitcnt vmcnt(" #Ncnt ")" ::: "memory"); \
    __builtin_amdgcn_sched_barrier(0); } while (0)

// c storage split: n<32 -> cA (upper half of out2), n>=32 -> cB (ws)
__device__ __forceinline__ float* c_ptr(int n, int t, int j, float* cA, float* cB) {
    return (n < 32) ? (cA + (((size_t)(n * 256 + t)) << 10) + j)
                    : (cB + (((size_t)((n - 32) * 256 + t)) << 10) + j);
}

// ---------------- prep kernels ----------------

// Packed row rp = j*4+g : [W_ih[g*H+j][0:512] ; W_hh[g*H+j][0:1024]] bf16
__global__ __launch_bounds__(256) void pack_weights(
    const float* __restrict__ W_ih, const float* __restrict__ W_hh,
    const float* __restrict__ b_ih, const float* __restrict__ b_hh,
    u16* __restrict__ Wp, float* __restrict__ bp)
{
    const int rp = blockIdx.x;            // 0..4095
    const int j = rp >> 2, g = rp & 3;
    const int src = g * H_ + j;
    const float* wi = W_ih + (size_t)src * I_;
    const float* wh = W_hh + (size_t)src * H_;
    u16* dst = Wp + (size_t)rp * (I_ + H_);
    for (int k = threadIdx.x; k < I_; k += 256) dst[k] = f2bf(wi[k]);
    for (int k = threadIdx.x; k < H_; k += 256) dst[I_ + k] = f2bf(wh[k]);
    if (threadIdx.x == 0) bp[rp] = b_ih[src] + b_hh[src];
}

__global__ __launch_bounds__(256) void conv_x(
    const float* __restrict__ x, u16* __restrict__ x_tb)
{
    const int t = blockIdx.x, n = blockIdx.y;
    const float* s = x + ((size_t)n * T_ + t) * I_;
    u16* d = x_tb + ((size_t)t * N_ + n) * I_;
    for (int k = threadIdx.x; k < I_; k += 256) d[k] = f2bf(s[k]);
}

__global__ __launch_bounds__(256) void conv_wout(
    const float* __restrict__ W, u16* __restrict__ Wb)
{
    const size_t base = (size_t)blockIdx.x * 1024 + threadIdx.x;
    #pragma unroll
    for (int q = 0; q < 4; ++q) Wb[base + q * 256] = f2bf(W[base + q * 256]);
}

// hxbf[n][j] = bf16(hx[n,0,j])   (UNscaled; only read by rows with r=1)
__global__ __launch_bounds__(256) void conv_hx(
    const float* __restrict__ hx, u16* __restrict__ hxbf)
{
    const int idx = blockIdx.x * 256 + threadIdx.x;   // 65536
    const int n = idx >> 10, j = idx & (H_ - 1);
    hxbf[idx] = f2bf(hx[(size_t)n * T_ * H_ + j]);
}

// rel[n,t] = 0 if is_init, else distance to previous reset (t+1 if none).
__global__ __launch_bounds__(256) void prep_rel(
    const int* __restrict__ is_init, u16* __restrict__ rel16)
{
    __shared__ u16 ii[256];
    const int n = blockIdx.x, t = threadIdx.x;
    ii[t] = (u16)(is_init[n * T_ + t] != 0);
    __syncthreads();
    int rel = t + 1;
    for (int d = 0; d <= t; ++d) {
        if (ii[t - d]) { rel = d; break; }
    }
    rel16[n * T_ + t] = (u16)rel;
}

// Per batch-group: LDS histogram of rel -> exclusive offsets -> scatter CSR.
__global__ __launch_bounds__(256) void prep_bucket(
    const u16* __restrict__ rel16, u16* __restrict__ entries, u32* __restrict__ offs)
{
    __shared__ u32 hist[258];
    __shared__ u32 offsh[258];
    const int g = blockIdx.x, tid = threadIdx.x;
    for (int i = tid; i < 258; i += 256) hist[i] = 0;
    __syncthreads();
    for (int i = tid; i < 4096; i += 256) {
        const int n = g * 16 + (i & 15), t = i >> 4;
        atomicAdd(&hist[rel16[n * T_ + t]], 1u);
    }
    __syncthreads();
    if (tid == 0) {
        u32 acc = 0;
        for (int s = 0; s < 258; ++s) { offsh[s] = acc; acc += hist[s]; }
    }
    __syncthreads();
    for (int i = tid; i < 258; i += 256) {
        offs[g * 258 + i] = offsh[i];
        hist[i] = offsh[i];          // reuse as scatter cursor
    }
    __syncthreads();
    for (int i = tid; i < 4096; i += 256) {
        const int n = g * 16 + (i & 15), t = i >> 4;
        const int rel = rel16[n * T_ + t];
        const u32 slot = atomicAdd(&hist[rel], 1u);
        entries[g * 4096 + slot] = (u16)((t << 6) | n);
    }
}

// ---------------- x-gate precompute: 256x256-tile GEMM [proven r11] ----------
__global__ __launch_bounds__(512) __attribute__((amdgpu_waves_per_eu(2, 2)))
void xgates_mfma(
    const u16* __restrict__ x_tb,   // [16384][512]
    const u16* __restrict__ Wp,     // [4096][1536] (x-part = first 512)
    const float* __restrict__ bp,   // [4096]
    u16* __restrict__ Xg)           // [16384][4096]
{
    __shared__ u16 bls[2][8192];    // 2 x 16KB, lane-major per 16-col tile
    const int bx = blockIdx.x, by = blockIdx.y;
    const int tid = threadIdx.x;
    const int v = tid >> 6, l = tid & 63;
    const int l15 = l & 15, lh = l >> 4;
    const int rowb = bx * 256 + v * 32;
    const int colb = by * 256;

    const u16* ap0 = x_tb + (size_t)(rowb + l15) * I_ + lh * 8;
    const u16* ap1 = x_tb + (size_t)(rowb + 16 + l15) * I_ + lh * 8;
    const u16* bs0 = Wp + (size_t)(colb + (2 * v) * 16 + l15) * 1536 + lh * 8;
    const u16* bs1 = Wp + (size_t)(colb + (2 * v + 1) * 16 + l15) * 1536 + lh * 8;

    f32x4 acc[2][16];
    #pragma unroll
    for (int m = 0; m < 2; ++m)
        #pragma unroll
        for (int nt = 0; nt < 16; ++nt) acc[m][nt] = f32x4{0.f, 0.f, 0.f, 0.f};

#define STAGEX(S, B) do { \
    gload_lds16n(bs0 + (S) * 32, (char*)bls[B] + (2 * v) * 1024); \
    gload_lds16n(bs1 + (S) * 32, (char*)bls[B] + (2 * v + 1) * 1024); } while (0)

    STAGEX(0, 0);
    VMW(0); __syncthreads();
    int buf = 0;
    for (int s = 0; s < 16; ++s) {
        if (s < 15) STAGEX(s + 1, buf ^ 1);
        bf16x8 a0 = *(const bf16x8*)(ap0 + s * 32);
        bf16x8 a1 = *(const bf16x8*)(ap1 + s * 32);
        const char* bb = (const char*)bls[buf];
        #pragma unroll
        for (int nt = 0; nt < 16; ++nt) {
            bf16x8 bfr = *(const bf16x8*)(bb + nt * 1024 + l * 16);
            acc[0][nt] = __builtin_amdgcn_mfma_f32_16x16x32_bf16(a0, bfr, acc[0][nt], 0, 0, 0);
            acc[1][nt] = __builtin_amdgcn_mfma_f32_16x16x32_bf16(a1, bfr, acc[1][nt], 0, 0, 0);
        }
        VMW(0); __syncthreads();
        buf ^= 1;
    }
#undef STAGEX

    #pragma unroll
    for (int nt = 0; nt < 16; ++nt) {
        const int col = colb + nt * 16 + l15;
        const float bo = bp[col];
        #pragma unroll
        for (int mt = 0; mt < 2; ++mt)
            #pragma unroll
            for (int rg = 0; rg < 4; ++rg) {
                const int row = rowb + mt * 16 + lh * 4 + rg;
                Xg[(size_t)row * 4096 + col] = f2bf(acc[mt][nt][rg] + bo);
            }
    }
}

// ---------------- segment-parallel LSTM: wave-autonomous tiles ---------------
// r14/r15 were LDS-BW-bound (256KB LDS traffic/tile ~= measured 2us/tile).
// New: each WAVE owns tile mt = v, v+4, ... independently. A-tile (16 rows x
// 1024 k) lives in 128 VGPRs (per-lane IC atomic loads); the wave runs all 4
// weight quarters (128 MFMA) against it, W-frags from LDS-resident weights
// [r13]. LDS traffic halves, ds_writes vanish, and the per-tile vmcnt-draining
// __syncthreads (the r15 regression mechanism) is eliminated entirely.
__global__ __launch_bounds__(256, 1) void lstm_seg(
    const u16* __restrict__ Xg,      // [16384][4096] bf16 (x-gates + biases)
    const u16* __restrict__ Wp,      // [4096][1536]
    const float* __restrict__ cx,    // (N,T,H) fp32
    const u16* __restrict__ hxbf,    // [64][1024] bf16
    const u16* __restrict__ entries, // [4][4096] CSR by rel
    const u32* __restrict__ offs,    // [4][258]
    u16* __restrict__ hs,            // [64][256][1024] bf16 (out2 lower)
    float* __restrict__ cA,          // [32][256][1024] f32 (out2 upper, n<32)
    float* __restrict__ cB,          // [32][256][1024] f32 (ws, n>=32)
    float* __restrict__ c_final,     // [64][1024] f32
    u32* __restrict__ flags)         // [4][64] x16-spaced
{
    __shared__ u16 wls[65536];       // 128 KB: h-part weights, quarter-major
    const int tid = threadIdx.x;
    const int v = tid >> 6, l = tid & 63;
    const int l15 = l & 15, lh = l >> 4;
    const int u = blockIdx.x & 63, g = blockIdx.x >> 6;

    // preload weights [r13-proven]: wave v stages quarter v (rows u*64+v*16..+15)
    {
        const u16* src = Wp + (size_t)(u * 64 + v * 16 + l15) * 1536 + I_ + lh * 8;
        char* dst = (char*)wls + v * 32768;
        #pragma unroll
        for (int kk = 0; kk < 32; ++kk)
            gload_lds16n(src + kk * 32, dst + kk * 1024);
    }

    const u16* gent = entries + g * 4096;
    const u32* goff = offs + g * 258;
    u32* gflags = flags + g * 64 * 16;
    const char* wlsb = (const char*)wls;

    VMW(0);
    __syncthreads();

    // ---- s = 0: elementwise rows (h_prev = c_prev = 0), 2 units per thread
    {
        const int m0 = (int)goff[1];
        const int gtid = u * 256 + tid;       // 0..16383 within group
        for (int cell = gtid; cell < m0 * 512; cell += 64 * 256) {
            const int ri = cell >> 9, jj = cell & 511;
            const int j = jj * 2;
            const u16 e = gent[ri];
            const int t = e >> 6, n = e & 63;
            const u16* xp = Xg + ((size_t)t * 64 + n) * 4096 + 4 * j;
            const u16x4 xa = *(const u16x4*)(xp);
            const u16x4 xb = *(const u16x4*)(xp + 4);
            const float c0 = sigf(bf2f(xa[0])) * tanhfast(bf2f(xa[2]));
            const float h0 = sigf(bf2f(xa[3])) * tanhfast(c0);
            const float c1 = sigf(bf2f(xb[0])) * tanhfast(bf2f(xb[2]));
            const float h1 = sigf(bf2f(xb[3])) * tanhfast(c1);
            const size_t hrow = ((size_t)n * 256 + t) * 1024;
            __hip_atomic_store((u32*)(hs + hrow + j),
                               (u32)f2bf(h0) | ((u32)f2bf(h1) << 16),
                               __ATOMIC_RELAXED, __HIP_MEMORY_SCOPE_AGENT);
            __hip_atomic_store((u32*)c_ptr(n, t, j, cA, cB), __float_as_uint(c0),
                               __ATOMIC_RELAXED, __HIP_MEMORY_SCOPE_AGENT);
            __hip_atomic_store((u32*)c_ptr(n, t, j + 1, cA, cB), __float_as_uint(c1),
                               __ATOMIC_RELAXED, __HIP_MEMORY_SCOPE_AGENT);
            if (t == T_ - 1) {
                c_final[n * H_ + j] = c0;
                c_final[n * H_ + j + 1] = c1;
            }
        }
    }
    VMW(0);
    __syncthreads();
    if (tid == 0)
        __hip_atomic_store(gflags + u * 16, 1u,
                           __ATOMIC_RELAXED, __HIP_MEMORY_SCOPE_AGENT);
    if (tid < 64) {
        while (__hip_atomic_load(gflags + tid * 16, __ATOMIC_RELAXED,
                                 __HIP_MEMORY_SCOPE_AGENT) < 1u)
            __builtin_amdgcn_s_sleep(1);
    }
    __syncthreads();
    __builtin_amdgcn_sched_barrier(0);

    union AU { u64 q[2]; bf16x8 b; };

    // ---- iterations s = 1.. (exact bound: rows with rel >= s exist)
    for (int s = 1; s <= 256; ++s) {
        if (goff[s] >= 4096u) break;
        const int base = (int)goff[s];
        const int last = (int)goff[s + 1] - 1;
        const int ntiles = ((last + 1 - base) + 15) >> 4;

        // wave-autonomous: wave v handles tiles v, v+4, ...
        for (int mt = v; mt < ntiles; mt += 4) {
            const int ridx = base + mt * 16 + l15;
            const bool valid = (ridx <= last);
            const u16 e = gent[valid ? ridx : last];
            const int t = e >> 6, n = e & 63;

            // A-tile row (this lane's m-row) -> 32 x 16B into registers (IC)
            const u16* rowsrc = (t == 0) ? (hxbf + n * 1024)
                               : (hs + ((size_t)n * 256 + (t - 1)) * 1024);
            const char* lsrc = (const char*)rowsrc + lh * 16;
            AU a[32];
            #pragma unroll
            for (int kk = 0; kk < 32; ++kk) {
                a[kk].q[0] = __hip_atomic_load((const u64*)(lsrc + kk * 64),
                                 __ATOMIC_RELAXED, __HIP_MEMORY_SCOPE_AGENT);
                a[kk].q[1] = __hip_atomic_load((const u64*)(lsrc + kk * 64 + 8),
                                 __ATOMIC_RELAXED, __HIP_MEMORY_SCOPE_AGENT);
            }

            // per-quarter epilogue operands (hide under A-load latency / MFMA)
            const u16* xrow = Xg + ((size_t)t * 64 + n) * 4096;
            u16x4 xg[4]; float cprev[4];
            #pragma unroll
            for (int q = 0; q < 4; ++q) {
                const int jbq = u * 16 + q * 4 + lh;
                xg[q] = *(const u16x4*)(xrow + 4 * jbq);
                const float* cp = (t == 0) ? (cx + (size_t)n * T_ * H_ + jbq)
                                           : c_ptr(n, t - 1, jbq, cA, cB);
                cprev[q] = __uint_as_float(__hip_atomic_load((const u32*)cp,
                               __ATOMIC_RELAXED, __HIP_MEMORY_SCOPE_AGENT));
            }

            // 4 quarters x 32 kk MFMA; W-frags from LDS (contiguous 1KB/read)
            f32x4 acc[4];
            #pragma unroll
            for (int q = 0; q < 4; ++q) acc[q] = f32x4{0.f, 0.f, 0.f, 0.f};
            #pragma unroll
            for (int q = 0; q < 4; ++q) {
                #pragma unroll
                for (int kk = 0; kk < 32; ++kk) {
                    bf16x8 wf = *(const bf16x8*)(wlsb + q * 32768 + kk * 1024 + l * 16);
                    acc[q] = __builtin_amdgcn_mfma_f32_16x16x32_bf16(wf, a[kk].b, acc[q], 0, 0, 0);
                }
            }

            // epilogue: 4 cells/lane (unit u*16+q*4+lh, m-row l15)
            #pragma unroll
            for (int q = 0; q < 4; ++q) {
                const int jbq = u * 16 + q * 4 + lh;
                const float ig = acc[q][0] + bf2f(xg[q][0]);
                const float fg = acc[q][1] + bf2f(xg[q][1]);
                const float gg = acc[q][2] + bf2f(xg[q][2]);
                const float og = acc[q][3] + bf2f(xg[q][3]);
                const float cn = sigf(fg) * cprev[q] + sigf(ig) * tanhfast(gg);
                const float hv = sigf(og) * tanhfast(cn);

                const float hvp = __shfl_down(hv, 16);
                if (valid && !(lh & 1)) {
                    __hip_atomic_store((u32*)(hs + ((size_t)n * 256 + t) * 1024 + jbq),
                                       (u32)f2bf(hv) | ((u32)f2bf(hvp) << 16),
                                       __ATOMIC_RELAXED, __HIP_MEMORY_SCOPE_AGENT);
                }
                if (valid) {
                    __hip_atomic_store((u32*)c_ptr(n, t, jbq, cA, cB),
                                       __float_as_uint(cn),
                                       __ATOMIC_RELAXED, __HIP_MEMORY_SCOPE_AGENT);
                    if (t == T_ - 1) c_final[n * H_ + jbq] = cn;
                }
            }
        }

        // group barrier: phase s complete
        VMW(0);
        __syncthreads();
        if (tid == 0)
            __hip_atomic_store(gflags + u * 16, (u32)(s + 1),
                               __ATOMIC_RELAXED, __HIP_MEMORY_SCOPE_AGENT);
        if (tid < 64) {
            while (__hip_atomic_load(gflags + tid * 16, __ATOMIC_RELAXED,
                                     __HIP_MEMORY_SCOPE_AGENT) < (u32)(s + 1))
                __builtin_amdgcn_s_sleep(1);
        }
        __syncthreads();
        __builtin_amdgcn_sched_barrier(0);
    }
}

// ---------------- output projection: 256x256-tile GEMM + mish [proven r11] ---
__global__ __launch_bounds__(512) __attribute__((amdgpu_waves_per_eu(2, 2)))
void out_proj_mfma(
    const u16* __restrict__ hs,     // [16384][1024]
    const u16* __restrict__ Wo,     // [1024][1024]
    const float* __restrict__ b_out,
    float* __restrict__ out0)       // [16384][1024]
{
    __shared__ u16 bls[2][8192];    // 2 x 16KB
    const int bx = blockIdx.x, by = blockIdx.y;
    const int tid = threadIdx.x;
    const int v = tid >> 6, l = tid & 63;
    const int l15 = l & 15, lh = l >> 4;
    const int rowb = bx * 256 + v * 32;
    const int colb = by * 256;

    const u16* ap0 = hs + (size_t)(rowb + l15) * H_ + lh * 8;
    const u16* ap1 = hs + (size_t)(rowb + 16 + l15) * H_ + lh * 8;
    const u16* bs0 = Wo + (size_t)(colb + (2 * v) * 16 + l15) * H_ + lh * 8;
    const u16* bs1 = Wo + (size_t)(colb + (2 * v + 1) * 16 + l15) * H_ + lh * 8;

    f32x4 acc[2][16];
    #pragma unroll
    for (int m = 0; m < 2; ++m)
        #pragma unroll
        for (int nt = 0; nt < 16; ++nt) acc[m][nt] = f32x4{0.f, 0.f, 0.f, 0.f};

#define STAGEO(S, B) do { \
    gload_lds16n(bs0 + (S) * 32, (char*)bls[B] + (2 * v) * 1024); \
    gload_lds16n(bs1 + (S) * 32, (char*)bls[B] + (2 * v + 1) * 1024); } while (0)

    STAGEO(0, 0);
    VMW(0); __syncthreads();
    int buf = 0;
    for (int s = 0; s < 32; ++s) {
        if (s < 31) STAGEO(s + 1, buf ^ 1);
        bf16x8 a0 = *(const bf16x8*)(ap0 + s * 32);
        bf16x8 a1 = *(const bf16x8*)(ap1 + s * 32);
        const char* bb = (const char*)bls[buf];
        #pragma unroll
        for (int nt = 0; nt < 16; ++nt) {
            bf16x8 bfr = *(const bf16x8*)(bb + nt * 1024 + l * 16);
            acc[0][nt] = __builtin_amdgcn_mfma_f32_16x16x32_bf16(a0, bfr, acc[0][nt], 0, 0, 0);
            acc[1][nt] = __builtin_amdgcn_mfma_f32_16x16x32_bf16(a1, bfr, acc[1][nt], 0, 0, 0);
        }
        VMW(0); __syncthreads();
        buf ^= 1;
    }
#undef STAGEO

    #pragma unroll
    for (int nt = 0; nt < 16; ++nt) {
        const int col = colb + nt * 16 + l15;
        const float bo = b_out[col];
        #pragma unroll
        for (int mt = 0; mt < 2; ++mt)
            #pragma unroll
            for (int rg = 0; rg < 4; ++rg) {
                const int row = rowb + mt * 16 + lh * 4 + rg;
                const float y = acc[mt][nt][rg] + bo;
                const float sp = (y > 15.f) ? y : log1pf(__expf(y));
                out0[(size_t)row * H_ + col] = y * tanhfast(sp);
            }
    }
}

// out1 = broadcast hs[:,255,:]  (hs in out2 region — MUST run before bcast_c)
__global__ __launch_bounds__(256) void bcast_h(
    const u16* __restrict__ hs, float* __restrict__ out1)
{
    const size_t total = (size_t)N_ * T_ * H_;
    for (size_t idx = (size_t)blockIdx.x * 256 + threadIdx.x; idx < total;
         idx += (size_t)gridDim.x * 256) {
        const int n = (int)(idx >> 18);
        const int j = (int)(idx & (H_ - 1));
        out1[idx] = bf2f(hs[((size_t)n * T_ + (T_ - 1)) * H_ + j]);
    }
}

__global__ __launch_bounds__(256) void bcast_c(
    const float* __restrict__ c_final, float* __restrict__ out2)
{
    const size_t total = (size_t)N_ * T_ * H_;
    for (size_t idx = (size_t)blockIdx.x * 256 + threadIdx.x; idx < total;
         idx += (size_t)gridDim.x * 256) {
        const int n = (int)(idx >> 18);
        const int j = (int)(idx & (H_ - 1));
        out2[idx] = c_final[n * H_ + j];
    }
}

extern "C" void kernel_launch(void* const* d_in, const int* in_sizes, int n_in,
                              void* d_out, int out_size, void* d_ws, size_t ws_size,
                              hipStream_t stream) {
    const float* x      = (const float*)d_in[0];
    const int*   is_ini = (const int*)  d_in[1];
    const float* hx     = (const float*)d_in[2];
    const float* cx     = (const float*)d_in[3];
    const float* W_ih   = (const float*)d_in[4];
    const float* W_hh   = (const float*)d_in[5];
    const float* b_ih   = (const float*)d_in[6];
    const float* b_hh   = (const float*)d_in[7];
    const float* W_out  = (const float*)d_in[8];
    const float* b_out  = (const float*)d_in[9];

    float* out0 = (float*)d_out;
    float* out1 = out0 + (size_t)N_ * T_ * H_;
    float* out2 = out1 + (size_t)N_ * T_ * H_;

    char* ws = (char*)d_ws;
    u16*   x_tb    = (u16*)  (ws + 0);          // 16,777,216
    u16*   Wp      = (u16*)  (ws + 16777216);   // 12,582,912
    float* bp      = (float*)(ws + 29360128);   // 16,384
    u16*   Wo_b    = (u16*)  (ws + 29376512);   // 2,097,152
    float* c_final = (float*)(ws + 31473664);   // 262,144
    u16*   hxbf    = (u16*)  (ws + 31735808);   // 131,072
    u16*   rel16   = (u16*)  (ws + 31866880);   // 32,768
    u16*   entries = (u16*)  (ws + 31899648);   // 32,768
    u32*   offs    = (u32*)  (ws + 31932416);   // 4,352 (pad)
    u32*   flags   = (u32*)  (ws + 31945472);   // 16,384   [4][64] x16-spaced
    float* cB      = (float*)(ws + 31961856);   // 33,554,432 (c for n>=32)
                                                // ws end ~65.5 MB (r2-proven size)

    u16*   Xg = (u16*)out0;             // 134.2 MB scratch (out0+out1), consumed
    u16*   hs = (u16*)out2;             // 33.55 MB (out2 lower half)
    float* cA = (float*)(out2 + (size_t)32 * 256 * 1024);  // out2 upper (n<32)

    hipMemsetAsync(flags, 0, 16384, stream);
    pack_weights<<<4096, 256, 0, stream>>>(W_ih, W_hh, b_ih, b_hh, Wp, bp);
    conv_x<<<dim3(T_, N_), 256, 0, stream>>>(x, x_tb);
    conv_wout<<<1024, 256, 0, stream>>>(W_out, Wo_b);
    conv_hx<<<256, 256, 0, stream>>>(hx, hxbf);
    prep_rel<<<64, 256, 0, stream>>>(is_ini, rel16);
    prep_bucket<<<4, 256, 0, stream>>>(rel16, entries, offs);

    xgates_mfma<<<dim3(64, 16), 512, 0, stream>>>(x_tb, Wp, bp, Xg);

    lstm_seg<<<256, 256, 0, stream>>>(Xg, Wp, cx, hxbf, entries, offs,
                                      hs, cA, cB, c_final, flags);

    out_proj_mfma<<<dim3(64, 4), 512, 0, stream>>>(hs, Wo_b, b_out, out0);
    bcast_h<<<2048, 256, 0, stream>>>(hs, out1);
    bcast_c<<<2048, 256, 0, stream>>>(c_final, out2);
}

// Round 17
// 1067.077 us; speedup vs baseline: 1.4127x; 1.1106x over previous
//
#include <hip/hip_runtime.h>
#include <math.h>

#define N_ 64
#define T_ 256
#define I_ 512
#define H_ 1024

typedef unsigned short u16;
typedef unsigned int u32;
typedef unsigned long long u64;
typedef short bf16x8 __attribute__((ext_vector_type(8)));
typedef float f32x4 __attribute__((ext_vector_type(4)));
typedef u16 u16x4 __attribute__((ext_vector_type(4)));

__device__ __forceinline__ u16 f2bf(float f) {
    union { float f; unsigned int u; } x; x.f = f;
    unsigned int r = (x.u + 0x7FFFu + ((x.u >> 16) & 1u)) >> 16;
    return (u16)r;
}
__device__ __forceinline__ float bf2f(u16 u) {
    union { unsigned int u; float f; } x; x.u = ((unsigned int)u) << 16;
    return x.f;
}
__device__ __forceinline__ float sigf(float v) {
    return 1.0f / (1.0f + __expf(-v));
}
__device__ __forceinline__ float tanhfast(float x) {
    float e = __expf(2.0f * x);
    return 1.0f - 2.0f / (e + 1.0f);   // NaN-free at +-inf
}

// cached global->LDS (weight staging)
__device__ __forceinline__ void gload_lds16n(const void* g, void* l) {
    __builtin_amdgcn_global_load_lds(
        (__attribute__((address_space(1))) void*)(g),
        (__attribute__((address_space(3))) void*)(l), 16, 0, 0);
}

#define VMW(Ncnt) do { \
    asm volatile("s_waitcnt vmcnt(" #Ncnt ")" ::: "memory"); \
    __builtin_amdgcn_sched_barrier(0); } while (0)

// c storage split: n<32 -> cA (upper half of out2), n>=32 -> cB (ws)
__device__ __forceinline__ float* c_ptr(int n, int t, int j, float* cA, float* cB) {
    return (n < 32) ? (cA + (((size_t)(n * 256 + t)) << 10) + j)
                    : (cB + (((size_t)((n - 32) * 256 + t)) << 10) + j);
}

// ---------------- prep kernels ----------------

// Packed row rp = j*4+g : [W_ih[g*H+j][0:512] ; W_hh[g*H+j][0:1024]] bf16
__global__ __launch_bounds__(256) void pack_weights(
    const float* __restrict__ W_ih, const float* __restrict__ W_hh,
    const float* __restrict__ b_ih, const float* __restrict__ b_hh,
    u16* __restrict__ Wp, float* __restrict__ bp)
{
    const int rp = blockIdx.x;            // 0..4095
    const int j = rp >> 2, g = rp & 3;
    const int src = g * H_ + j;
    const float* wi = W_ih + (size_t)src * I_;
    const float* wh = W_hh + (size_t)src * H_;
    u16* dst = Wp + (size_t)rp * (I_ + H_);
    for (int k = threadIdx.x; k < I_; k += 256) dst[k] = f2bf(wi[k]);
    for (int k = threadIdx.x; k < H_; k += 256) dst[I_ + k] = f2bf(wh[k]);
    if (threadIdx.x == 0) bp[rp] = b_ih[src] + b_hh[src];
}

__global__ __launch_bounds__(256) void conv_x(
    const float* __restrict__ x, u16* __restrict__ x_tb)
{
    const int t = blockIdx.x, n = blockIdx.y;
    const float* s = x + ((size_t)n * T_ + t) * I_;
    u16* d = x_tb + ((size_t)t * N_ + n) * I_;
    for (int k = threadIdx.x; k < I_; k += 256) d[k] = f2bf(s[k]);
}

__global__ __launch_bounds__(256) void conv_wout(
    const float* __restrict__ W, u16* __restrict__ Wb)
{
    const size_t base = (size_t)blockIdx.x * 1024 + threadIdx.x;
    #pragma unroll
    for (int q = 0; q < 4; ++q) Wb[base + q * 256] = f2bf(W[base + q * 256]);
}

// hxbf[n][j] = bf16(hx[n,0,j])   (UNscaled; only read by rows with r=1)
__global__ __launch_bounds__(256) void conv_hx(
    const float* __restrict__ hx, u16* __restrict__ hxbf)
{
    const int idx = blockIdx.x * 256 + threadIdx.x;   // 65536
    const int n = idx >> 10, j = idx & (H_ - 1);
    hxbf[idx] = f2bf(hx[(size_t)n * T_ * H_ + j]);
}

// rel[n,t] = 0 if is_init, else distance to previous reset (t+1 if none).
__global__ __launch_bounds__(256) void prep_rel(
    const int* __restrict__ is_init, u16* __restrict__ rel16)
{
    __shared__ u16 ii[256];
    const int n = blockIdx.x, t = threadIdx.x;
    ii[t] = (u16)(is_init[n * T_ + t] != 0);
    __syncthreads();
    int rel = t + 1;
    for (int d = 0; d <= t; ++d) {
        if (ii[t - d]) { rel = d; break; }
    }
    rel16[n * T_ + t] = (u16)rel;
}

// Per batch-group: LDS histogram of rel -> exclusive offsets -> scatter CSR.
__global__ __launch_bounds__(256) void prep_bucket(
    const u16* __restrict__ rel16, u16* __restrict__ entries, u32* __restrict__ offs)
{
    __shared__ u32 hist[258];
    __shared__ u32 offsh[258];
    const int g = blockIdx.x, tid = threadIdx.x;
    for (int i = tid; i < 258; i += 256) hist[i] = 0;
    __syncthreads();
    for (int i = tid; i < 4096; i += 256) {
        const int n = g * 16 + (i & 15), t = i >> 4;
        atomicAdd(&hist[rel16[n * T_ + t]], 1u);
    }
    __syncthreads();
    if (tid == 0) {
        u32 acc = 0;
        for (int s = 0; s < 258; ++s) { offsh[s] = acc; acc += hist[s]; }
    }
    __syncthreads();
    for (int i = tid; i < 258; i += 256) {
        offs[g * 258 + i] = offsh[i];
        hist[i] = offsh[i];          // reuse as scatter cursor
    }
    __syncthreads();
    for (int i = tid; i < 4096; i += 256) {
        const int n = g * 16 + (i & 15), t = i >> 4;
        const int rel = rel16[n * T_ + t];
        const u32 slot = atomicAdd(&hist[rel], 1u);
        entries[g * 4096 + slot] = (u16)((t << 6) | n);
    }
}

// ---------------- x-gate precompute: 256x256-tile GEMM [proven r11] ----------
__global__ __launch_bounds__(512) __attribute__((amdgpu_waves_per_eu(2, 2)))
void xgates_mfma(
    const u16* __restrict__ x_tb,   // [16384][512]
    const u16* __restrict__ Wp,     // [4096][1536] (x-part = first 512)
    const float* __restrict__ bp,   // [4096]
    u16* __restrict__ Xg)           // [16384][4096]
{
    __shared__ u16 bls[2][8192];    // 2 x 16KB, lane-major per 16-col tile
    const int bx = blockIdx.x, by = blockIdx.y;
    const int tid = threadIdx.x;
    const int v = tid >> 6, l = tid & 63;
    const int l15 = l & 15, lh = l >> 4;
    const int rowb = bx * 256 + v * 32;
    const int colb = by * 256;

    const u16* ap0 = x_tb + (size_t)(rowb + l15) * I_ + lh * 8;
    const u16* ap1 = x_tb + (size_t)(rowb + 16 + l15) * I_ + lh * 8;
    const u16* bs0 = Wp + (size_t)(colb + (2 * v) * 16 + l15) * 1536 + lh * 8;
    const u16* bs1 = Wp + (size_t)(colb + (2 * v + 1) * 16 + l15) * 1536 + lh * 8;

    f32x4 acc[2][16];
    #pragma unroll
    for (int m = 0; m < 2; ++m)
        #pragma unroll
        for (int nt = 0; nt < 16; ++nt) acc[m][nt] = f32x4{0.f, 0.f, 0.f, 0.f};

#define STAGEX(S, B) do { \
    gload_lds16n(bs0 + (S) * 32, (char*)bls[B] + (2 * v) * 1024); \
    gload_lds16n(bs1 + (S) * 32, (char*)bls[B] + (2 * v + 1) * 1024); } while (0)

    STAGEX(0, 0);
    VMW(0); __syncthreads();
    int buf = 0;
    for (int s = 0; s < 16; ++s) {
        if (s < 15) STAGEX(s + 1, buf ^ 1);
        bf16x8 a0 = *(const bf16x8*)(ap0 + s * 32);
        bf16x8 a1 = *(const bf16x8*)(ap1 + s * 32);
        const char* bb = (const char*)bls[buf];
        #pragma unroll
        for (int nt = 0; nt < 16; ++nt) {
            bf16x8 bfr = *(const bf16x8*)(bb + nt * 1024 + l * 16);
            acc[0][nt] = __builtin_amdgcn_mfma_f32_16x16x32_bf16(a0, bfr, acc[0][nt], 0, 0, 0);
            acc[1][nt] = __builtin_amdgcn_mfma_f32_16x16x32_bf16(a1, bfr, acc[1][nt], 0, 0, 0);
        }
        VMW(0); __syncthreads();
        buf ^= 1;
    }
#undef STAGEX

    #pragma unroll
    for (int nt = 0; nt < 16; ++nt) {
        const int col = colb + nt * 16 + l15;
        const float bo = bp[col];
        #pragma unroll
        for (int mt = 0; mt < 2; ++mt)
            #pragma unroll
            for (int rg = 0; rg < 4; ++rg) {
                const int row = rowb + mt * 16 + lh * 4 + rg;
                Xg[(size_t)row * 4096 + col] = f2bf(acc[mt][nt][rg] + bo);
            }
    }
}

// ---------------- segment-parallel LSTM: wave tiles + CACHED A reads ---------
// r16 was IC-read-bound: 64 unit-WGs/group re-read the same A-tiles via
// L2-BYPASS loads (~1 GB IC traffic). Fix: plain cached loads for hs/c reads.
// Safe because each hs/c line is written exactly once per run (write-through
// agent stores -> IC) and read only in a LATER phase after the group barrier;
// kernel-dispatch boundaries invalidate L2 (HW-verified by the Xg path since
// r9). L2 now serves the 8 same-group WGs per XCD: IC traffic drops ~8x.
__global__ __launch_bounds__(256, 1) void lstm_seg(
    const u16* __restrict__ Xg,      // [16384][4096] bf16 (x-gates + biases)
    const u16* __restrict__ Wp,      // [4096][1536]
    const float* __restrict__ cx,    // (N,T,H) fp32
    const u16* __restrict__ hxbf,    // [64][1024] bf16
    const u16* __restrict__ entries, // [4][4096] CSR by rel
    const u32* __restrict__ offs,    // [4][258]
    u16* __restrict__ hs,            // [64][256][1024] bf16 (out2 lower)
    float* __restrict__ cA,          // [32][256][1024] f32 (out2 upper, n<32)
    float* __restrict__ cB,          // [32][256][1024] f32 (ws, n>=32)
    float* __restrict__ c_final,     // [64][1024] f32
    u32* __restrict__ flags)         // [4][64] x16-spaced
{
    __shared__ u16 wls[65536];       // 128 KB: h-part weights, quarter-major
    const int tid = threadIdx.x;
    const int v = tid >> 6, l = tid & 63;
    const int l15 = l & 15, lh = l >> 4;
    const int u = blockIdx.x & 63, g = blockIdx.x >> 6;

    // preload weights [r13-proven]: wave v stages quarter v (rows u*64+v*16..+15)
    {
        const u16* src = Wp + (size_t)(u * 64 + v * 16 + l15) * 1536 + I_ + lh * 8;
        char* dst = (char*)wls + v * 32768;
        #pragma unroll
        for (int kk = 0; kk < 32; ++kk)
            gload_lds16n(src + kk * 32, dst + kk * 1024);
    }

    const u16* gent = entries + g * 4096;
    const u32* goff = offs + g * 258;
    u32* gflags = flags + g * 64 * 16;
    const char* wlsb = (const char*)wls;

    VMW(0);
    __syncthreads();

    // ---- s = 0: elementwise rows (h_prev = c_prev = 0), 2 units per thread
    {
        const int m0 = (int)goff[1];
        const int gtid = u * 256 + tid;       // 0..16383 within group
        for (int cell = gtid; cell < m0 * 512; cell += 64 * 256) {
            const int ri = cell >> 9, jj = cell & 511;
            const int j = jj * 2;
            const u16 e = gent[ri];
            const int t = e >> 6, n = e & 63;
            const u16* xp = Xg + ((size_t)t * 64 + n) * 4096 + 4 * j;
            const u16x4 xa = *(const u16x4*)(xp);
            const u16x4 xb = *(const u16x4*)(xp + 4);
            const float c0 = sigf(bf2f(xa[0])) * tanhfast(bf2f(xa[2]));
            const float h0 = sigf(bf2f(xa[3])) * tanhfast(c0);
            const float c1 = sigf(bf2f(xb[0])) * tanhfast(bf2f(xb[2]));
            const float h1 = sigf(bf2f(xb[3])) * tanhfast(c1);
            const size_t hrow = ((size_t)n * 256 + t) * 1024;
            __hip_atomic_store((u32*)(hs + hrow + j),
                               (u32)f2bf(h0) | ((u32)f2bf(h1) << 16),
                               __ATOMIC_RELAXED, __HIP_MEMORY_SCOPE_AGENT);
            __hip_atomic_store((u32*)c_ptr(n, t, j, cA, cB), __float_as_uint(c0),
                               __ATOMIC_RELAXED, __HIP_MEMORY_SCOPE_AGENT);
            __hip_atomic_store((u32*)c_ptr(n, t, j + 1, cA, cB), __float_as_uint(c1),
                               __ATOMIC_RELAXED, __HIP_MEMORY_SCOPE_AGENT);
            if (t == T_ - 1) {
                c_final[n * H_ + j] = c0;
                c_final[n * H_ + j + 1] = c1;
            }
        }
    }
    VMW(0);
    __syncthreads();
    if (tid == 0)
        __hip_atomic_store(gflags + u * 16, 1u,
                           __ATOMIC_RELAXED, __HIP_MEMORY_SCOPE_AGENT);
    if (tid < 64) {
        while (__hip_atomic_load(gflags + tid * 16, __ATOMIC_RELAXED,
                                 __HIP_MEMORY_SCOPE_AGENT) < 1u)
            __builtin_amdgcn_s_sleep(1);
    }
    __syncthreads();
    __builtin_amdgcn_sched_barrier(0);

    // ---- iterations s = 1.. (exact bound: rows with rel >= s exist)
    for (int s = 1; s <= 256; ++s) {
        if (goff[s] >= 4096u) break;
        const int base = (int)goff[s];
        const int last = (int)goff[s + 1] - 1;
        const int ntiles = ((last + 1 - base) + 15) >> 4;

        // wave-autonomous: wave v handles tiles v, v+4, ...
        for (int mt = v; mt < ntiles; mt += 4) {
            const int ridx = base + mt * 16 + l15;
            const bool valid = (ridx <= last);
            const u16 e = gent[valid ? ridx : last];
            const int t = e >> 6, n = e & 63;

            // A-tile row (this lane's m-row) -> 32 x 16B into registers.
            // PLAIN CACHED loads (L2 shares across the XCD's same-group WGs).
            const u16* rowsrc = (t == 0) ? (hxbf + n * 1024)
                               : (hs + ((size_t)n * 256 + (t - 1)) * 1024);
            const char* lsrc = (const char*)rowsrc + lh * 16;
            bf16x8 a[32];
            #pragma unroll
            for (int kk = 0; kk < 32; ++kk)
                a[kk] = *(const bf16x8*)(lsrc + kk * 64);

            // per-quarter epilogue operands (cached; hidden under MFMA)
            const u16* xrow = Xg + ((size_t)t * 64 + n) * 4096;
            u16x4 xg[4]; float cprev[4];
            #pragma unroll
            for (int q = 0; q < 4; ++q) {
                const int jbq = u * 16 + q * 4 + lh;
                xg[q] = *(const u16x4*)(xrow + 4 * jbq);
                const float* cp = (t == 0) ? (cx + (size_t)n * T_ * H_ + jbq)
                                           : c_ptr(n, t - 1, jbq, cA, cB);
                cprev[q] = *cp;
            }

            // 4 quarters x 32 kk MFMA; W-frags from LDS (contiguous 1KB/read)
            f32x4 acc[4];
            #pragma unroll
            for (int q = 0; q < 4; ++q) acc[q] = f32x4{0.f, 0.f, 0.f, 0.f};
            #pragma unroll
            for (int q = 0; q < 4; ++q) {
                #pragma unroll
                for (int kk = 0; kk < 32; ++kk) {
                    bf16x8 wf = *(const bf16x8*)(wlsb + q * 32768 + kk * 1024 + l * 16);
                    acc[q] = __builtin_amdgcn_mfma_f32_16x16x32_bf16(wf, a[kk], acc[q], 0, 0, 0);
                }
            }

            // epilogue: 4 cells/lane (unit u*16+q*4+lh, m-row l15)
            #pragma unroll
            for (int q = 0; q < 4; ++q) {
                const int jbq = u * 16 + q * 4 + lh;
                const float ig = acc[q][0] + bf2f(xg[q][0]);
                const float fg = acc[q][1] + bf2f(xg[q][1]);
                const float gg = acc[q][2] + bf2f(xg[q][2]);
                const float og = acc[q][3] + bf2f(xg[q][3]);
                const float cn = sigf(fg) * cprev[q] + sigf(ig) * tanhfast(gg);
                const float hv = sigf(og) * tanhfast(cn);

                const float hvp = __shfl_down(hv, 16);
                if (valid && !(lh & 1)) {
                    __hip_atomic_store((u32*)(hs + ((size_t)n * 256 + t) * 1024 + jbq),
                                       (u32)f2bf(hv) | ((u32)f2bf(hvp) << 16),
                                       __ATOMIC_RELAXED, __HIP_MEMORY_SCOPE_AGENT);
                }
                if (valid) {
                    __hip_atomic_store((u32*)c_ptr(n, t, jbq, cA, cB),
                                       __float_as_uint(cn),
                                       __ATOMIC_RELAXED, __HIP_MEMORY_SCOPE_AGENT);
                    if (t == T_ - 1) c_final[n * H_ + jbq] = cn;
                }
            }
        }

        // group barrier: phase s complete
        VMW(0);
        __syncthreads();
        if (tid == 0)
            __hip_atomic_store(gflags + u * 16, (u32)(s + 1),
                               __ATOMIC_RELAXED, __HIP_MEMORY_SCOPE_AGENT);
        if (tid < 64) {
            while (__hip_atomic_load(gflags + tid * 16, __ATOMIC_RELAXED,
                                     __HIP_MEMORY_SCOPE_AGENT) < (u32)(s + 1))
                __builtin_amdgcn_s_sleep(1);
        }
        __syncthreads();
        __builtin_amdgcn_sched_barrier(0);
    }
}

// ---------------- output projection: 256x256-tile GEMM + mish [proven r11] ---
__global__ __launch_bounds__(512) __attribute__((amdgpu_waves_per_eu(2, 2)))
void out_proj_mfma(
    const u16* __restrict__ hs,     // [16384][1024]
    const u16* __restrict__ Wo,     // [1024][1024]
    const float* __restrict__ b_out,
    float* __restrict__ out0)       // [16384][1024]
{
    __shared__ u16 bls[2][8192];    // 2 x 16KB
    const int bx = blockIdx.x, by = blockIdx.y;
    const int tid = threadIdx.x;
    const int v = tid >> 6, l = tid & 63;
    const int l15 = l & 15, lh = l >> 4;
    const int rowb = bx * 256 + v * 32;
    const int colb = by * 256;

    const u16* ap0 = hs + (size_t)(rowb + l15) * H_ + lh * 8;
    const u16* ap1 = hs + (size_t)(rowb + 16 + l15) * H_ + lh * 8;
    const u16* bs0 = Wo + (size_t)(colb + (2 * v) * 16 + l15) * H_ + lh * 8;
    const u16* bs1 = Wo + (size_t)(colb + (2 * v + 1) * 16 + l15) * H_ + lh * 8;

    f32x4 acc[2][16];
    #pragma unroll
    for (int m = 0; m < 2; ++m)
        #pragma unroll
        for (int nt = 0; nt < 16; ++nt) acc[m][nt] = f32x4{0.f, 0.f, 0.f, 0.f};

#define STAGEO(S, B) do { \
    gload_lds16n(bs0 + (S) * 32, (char*)bls[B] + (2 * v) * 1024); \
    gload_lds16n(bs1 + (S) * 32, (char*)bls[B] + (2 * v + 1) * 1024); } while (0)

    STAGEO(0, 0);
    VMW(0); __syncthreads();
    int buf = 0;
    for (int s = 0; s < 32; ++s) {
        if (s < 31) STAGEO(s + 1, buf ^ 1);
        bf16x8 a0 = *(const bf16x8*)(ap0 + s * 32);
        bf16x8 a1 = *(const bf16x8*)(ap1 + s * 32);
        const char* bb = (const char*)bls[buf];
        #pragma unroll
        for (int nt = 0; nt < 16; ++nt) {
            bf16x8 bfr = *(const bf16x8*)(bb + nt * 1024 + l * 16);
            acc[0][nt] = __builtin_amdgcn_mfma_f32_16x16x32_bf16(a0, bfr, acc[0][nt], 0, 0, 0);
            acc[1][nt] = __builtin_amdgcn_mfma_f32_16x16x32_bf16(a1, bfr, acc[1][nt], 0, 0, 0);
        }
        VMW(0); __syncthreads();
        buf ^= 1;
    }
#undef STAGEO

    #pragma unroll
    for (int nt = 0; nt < 16; ++nt) {
        const int col = colb + nt * 16 + l15;
        const float bo = b_out[col];
        #pragma unroll
        for (int mt = 0; mt < 2; ++mt)
            #pragma unroll
            for (int rg = 0; rg < 4; ++rg) {
                const int row = rowb + mt * 16 + lh * 4 + rg;
                const float y = acc[mt][nt][rg] + bo;
                const float sp = (y > 15.f) ? y : log1pf(__expf(y));
                out0[(size_t)row * H_ + col] = y * tanhfast(sp);
            }
    }
}

// out1 = broadcast hs[:,255,:]  (hs in out2 region — MUST run before bcast_c)
__global__ __launch_bounds__(256) void bcast_h(
    const u16* __restrict__ hs, float* __restrict__ out1)
{
    const size_t total = (size_t)N_ * T_ * H_;
    for (size_t idx = (size_t)blockIdx.x * 256 + threadIdx.x; idx < total;
         idx += (size_t)gridDim.x * 256) {
        const int n = (int)(idx >> 18);
        const int j = (int)(idx & (H_ - 1));
        out1[idx] = bf2f(hs[((size_t)n * T_ + (T_ - 1)) * H_ + j]);
    }
}

__global__ __launch_bounds__(256) void bcast_c(
    const float* __restrict__ c_final, float* __restrict__ out2)
{
    const size_t total = (size_t)N_ * T_ * H_;
    for (size_t idx = (size_t)blockIdx.x * 256 + threadIdx.x; idx < total;
         idx += (size_t)gridDim.x * 256) {
        const int n = (int)(idx >> 18);
        const int j = (int)(idx & (H_ - 1));
        out2[idx] = c_final[n * H_ + j];
    }
}

extern "C" void kernel_launch(void* const* d_in, const int* in_sizes, int n_in,
                              void* d_out, int out_size, void* d_ws, size_t ws_size,
                              hipStream_t stream) {
    const float* x      = (const float*)d_in[0];
    const int*   is_ini = (const int*)  d_in[1];
    const float* hx     = (const float*)d_in[2];
    const float* cx     = (const float*)d_in[3];
    const float* W_ih   = (const float*)d_in[4];
    const float* W_hh   = (const float*)d_in[5];
    const float* b_ih   = (const float*)d_in[6];
    const float* b_hh   = (const float*)d_in[7];
    const float* W_out  = (const float*)d_in[8];
    const float* b_out  = (const float*)d_in[9];

    float* out0 = (float*)d_out;
    float* out1 = out0 + (size_t)N_ * T_ * H_;
    float* out2 = out1 + (size_t)N_ * T_ * H_;

    char* ws = (char*)d_ws;
    u16*   x_tb    = (u16*)  (ws + 0);          // 16,777,216
    u16*   Wp      = (u16*)  (ws + 16777216);   // 12,582,912
    float* bp      = (float*)(ws + 29360128);   // 16,384
    u16*   Wo_b    = (u16*)  (ws + 29376512);   // 2,097,152
    float* c_final = (float*)(ws + 31473664);   // 262,144
    u16*   hxbf    = (u16*)  (ws + 31735808);   // 131,072
    u16*   rel16   = (u16*)  (ws + 31866880);   // 32,768
    u16*   entries = (u16*)  (ws + 31899648);   // 32,768
    u32*   offs    = (u32*)  (ws + 31932416);   // 4,352 (pad)
    u32*   flags   = (u32*)  (ws + 31945472);   // 16,384   [4][64] x16-spaced
    float* cB      = (float*)(ws + 31961856);   // 33,554,432 (c for n>=32)
                                                // ws end ~65.5 MB (r2-proven size)

    u16*   Xg = (u16*)out0;             // 134.2 MB scratch (out0+out1), consumed
    u16*   hs = (u16*)out2;             // 33.55 MB (out2 lower half)
    float* cA = (float*)(out2 + (size_t)32 * 256 * 1024);  // out2 upper (n<32)

    hipMemsetAsync(flags, 0, 16384, stream);
    pack_weights<<<4096, 256, 0, stream>>>(W_ih, W_hh, b_ih, b_hh, Wp, bp);
    conv_x<<<dim3(T_, N_), 256, 0, stream>>>(x, x_tb);
    conv_wout<<<1024, 256, 0, stream>>>(W_out, Wo_b);
    conv_hx<<<256, 256, 0, stream>>>(hx, hxbf);
    prep_rel<<<64, 256, 0, stream>>>(is_ini, rel16);
    prep_bucket<<<4, 256, 0, stream>>>(rel16, entries, offs);

    xgates_mfma<<<dim3(64, 16), 512, 0, stream>>>(x_tb, Wp, bp, Xg);

    lstm_seg<<<256, 256, 0, stream>>>(Xg, Wp, cx, hxbf, entries, offs,
                                      hs, cA, cB, c_final, flags);

    out_proj_mfma<<<dim3(64, 4), 512, 0, stream>>>(hs, Wo_b, b_out, out0);
    bcast_h<<<2048, 256, 0, stream>>>(hs, out1);
    bcast_c<<<2048, 256, 0, stream>>>(c_final, out2);
}

// Round 18
// 1000.062 us; speedup vs baseline: 1.5074x; 1.0670x over previous
//
#include <hip/hip_runtime.h>
#include <math.h>

#define N_ 64
#define T_ 256
#define I_ 512
#define H_ 1024

typedef unsigned short u16;
typedef unsigned int u32;
typedef unsigned long long u64;
typedef short bf16x8 __attribute__((ext_vector_type(8)));
typedef float f32x4 __attribute__((ext_vector_type(4)));
typedef u16 u16x4 __attribute__((ext_vector_type(4)));

__device__ __forceinline__ u16 f2bf(float f) {
    union { float f; unsigned int u; } x; x.f = f;
    unsigned int r = (x.u + 0x7FFFu + ((x.u >> 16) & 1u)) >> 16;
    return (u16)r;
}
__device__ __forceinline__ float bf2f(u16 u) {
    union { unsigned int u; float f; } x; x.u = ((unsigned int)u) << 16;
    return x.f;
}
__device__ __forceinline__ float sigf(float v) {
    return 1.0f / (1.0f + __expf(-v));
}
__device__ __forceinline__ float tanhfast(float x) {
    float e = __expf(2.0f * x);
    return 1.0f - 2.0f / (e + 1.0f);   // NaN-free at +-inf
}

// cached global->LDS (weight staging)
__device__ __forceinline__ void gload_lds16n(const void* g, void* l) {
    __builtin_amdgcn_global_load_lds(
        (__attribute__((address_space(1))) void*)(g),
        (__attribute__((address_space(3))) void*)(l), 16, 0, 0);
}

#define VMW(Ncnt) do { \
    asm volatile("s_waitcnt vmcnt(" #Ncnt ")" ::: "memory"); \
    __builtin_amdgcn_sched_barrier(0); } while (0)

// c storage split: n<32 -> cA (upper half of out2), n>=32 -> cB (ws)
__device__ __forceinline__ float* c_ptr(int n, int t, int j, float* cA, float* cB) {
    return (n < 32) ? (cA + (((size_t)(n * 256 + t)) << 10) + j)
                    : (cB + (((size_t)((n - 32) * 256 + t)) << 10) + j);
}

// ---------------- prep kernels ----------------

// Packed row rp = jp*4+g ; PERMUTED source: within each 16-block of packed unit
// index jp (loc = a*4+b), the true unit is loc' = b*4+a (involution). This makes
// a lane's 4 quarter-cells land on CONTIGUOUS true units -> coalesced stores.
__global__ __launch_bounds__(256) void pack_weights(
    const float* __restrict__ W_ih, const float* __restrict__ W_hh,
    const float* __restrict__ b_ih, const float* __restrict__ b_hh,
    u16* __restrict__ Wp, float* __restrict__ bp)
{
    const int rp = blockIdx.x;            // 0..4095
    const int g = rp & 3, jp = rp >> 2;
    const int loc = jp & 15;
    const int jsrc = (jp & ~15) + ((loc & 3) << 2) + (loc >> 2);
    const int src = g * H_ + jsrc;
    const float* wi = W_ih + (size_t)src * I_;
    const float* wh = W_hh + (size_t)src * H_;
    u16* dst = Wp + (size_t)rp * (I_ + H_);
    for (int k = threadIdx.x; k < I_; k += 256) dst[k] = f2bf(wi[k]);
    for (int k = threadIdx.x; k < H_; k += 256) dst[I_ + k] = f2bf(wh[k]);
    if (threadIdx.x == 0) bp[rp] = b_ih[src] + b_hh[src];
}

__global__ __launch_bounds__(256) void conv_x(
    const float* __restrict__ x, u16* __restrict__ x_tb)
{
    const int t = blockIdx.x, n = blockIdx.y;
    const float* s = x + ((size_t)n * T_ + t) * I_;
    u16* d = x_tb + ((size_t)t * N_ + n) * I_;
    for (int k = threadIdx.x; k < I_; k += 256) d[k] = f2bf(s[k]);
}

__global__ __launch_bounds__(256) void conv_wout(
    const float* __restrict__ W, u16* __restrict__ Wb)
{
    const size_t base = (size_t)blockIdx.x * 1024 + threadIdx.x;
    #pragma unroll
    for (int q = 0; q < 4; ++q) Wb[base + q * 256] = f2bf(W[base + q * 256]);
}

// hxbf[n][j] = bf16(hx[n,0,j])   (UNscaled; only read by rows with r=1)
__global__ __launch_bounds__(256) void conv_hx(
    const float* __restrict__ hx, u16* __restrict__ hxbf)
{
    const int idx = blockIdx.x * 256 + threadIdx.x;   // 65536
    const int n = idx >> 10, j = idx & (H_ - 1);
    hxbf[idx] = f2bf(hx[(size_t)n * T_ * H_ + j]);
}

// rel[n,t] = 0 if is_init, else distance to previous reset (t+1 if none).
__global__ __launch_bounds__(256) void prep_rel(
    const int* __restrict__ is_init, u16* __restrict__ rel16)
{
    __shared__ u16 ii[256];
    const int n = blockIdx.x, t = threadIdx.x;
    ii[t] = (u16)(is_init[n * T_ + t] != 0);
    __syncthreads();
    int rel = t + 1;
    for (int d = 0; d <= t; ++d) {
        if (ii[t - d]) { rel = d; break; }
    }
    rel16[n * T_ + t] = (u16)rel;
}

// Per batch-group: LDS histogram of rel -> exclusive offsets -> scatter CSR.
__global__ __launch_bounds__(256) void prep_bucket(
    const u16* __restrict__ rel16, u16* __restrict__ entries, u32* __restrict__ offs)
{
    __shared__ u32 hist[258];
    __shared__ u32 offsh[258];
    const int g = blockIdx.x, tid = threadIdx.x;
    for (int i = tid; i < 258; i += 256) hist[i] = 0;
    __syncthreads();
    for (int i = tid; i < 4096; i += 256) {
        const int n = g * 16 + (i & 15), t = i >> 4;
        atomicAdd(&hist[rel16[n * T_ + t]], 1u);
    }
    __syncthreads();
    if (tid == 0) {
        u32 acc = 0;
        for (int s = 0; s < 258; ++s) { offsh[s] = acc; acc += hist[s]; }
    }
    __syncthreads();
    for (int i = tid; i < 258; i += 256) {
        offs[g * 258 + i] = offsh[i];
        hist[i] = offsh[i];          // reuse as scatter cursor
    }
    __syncthreads();
    for (int i = tid; i < 4096; i += 256) {
        const int n = g * 16 + (i & 15), t = i >> 4;
        const int rel = rel16[n * T_ + t];
        const u32 slot = atomicAdd(&hist[rel], 1u);
        entries[g * 4096 + slot] = (u16)((t << 6) | n);
    }
}

// ---------------- x-gate precompute: 256x256-tile GEMM [proven r11] ----------
__global__ __launch_bounds__(512) __attribute__((amdgpu_waves_per_eu(2, 2)))
void xgates_mfma(
    const u16* __restrict__ x_tb,   // [16384][512]
    const u16* __restrict__ Wp,     // [4096][1536] (x-part = first 512)
    const float* __restrict__ bp,   // [4096]
    u16* __restrict__ Xg)           // [16384][4096]
{
    __shared__ u16 bls[2][8192];    // 2 x 16KB, lane-major per 16-col tile
    const int bx = blockIdx.x, by = blockIdx.y;
    const int tid = threadIdx.x;
    const int v = tid >> 6, l = tid & 63;
    const int l15 = l & 15, lh = l >> 4;
    const int rowb = bx * 256 + v * 32;
    const int colb = by * 256;

    const u16* ap0 = x_tb + (size_t)(rowb + l15) * I_ + lh * 8;
    const u16* ap1 = x_tb + (size_t)(rowb + 16 + l15) * I_ + lh * 8;
    const u16* bs0 = Wp + (size_t)(colb + (2 * v) * 16 + l15) * 1536 + lh * 8;
    const u16* bs1 = Wp + (size_t)(colb + (2 * v + 1) * 16 + l15) * 1536 + lh * 8;

    f32x4 acc[2][16];
    #pragma unroll
    for (int m = 0; m < 2; ++m)
        #pragma unroll
        for (int nt = 0; nt < 16; ++nt) acc[m][nt] = f32x4{0.f, 0.f, 0.f, 0.f};

#define STAGEX(S, B) do { \
    gload_lds16n(bs0 + (S) * 32, (char*)bls[B] + (2 * v) * 1024); \
    gload_lds16n(bs1 + (S) * 32, (char*)bls[B] + (2 * v + 1) * 1024); } while (0)

    STAGEX(0, 0);
    VMW(0); __syncthreads();
    int buf = 0;
    for (int s = 0; s < 16; ++s) {
        if (s < 15) STAGEX(s + 1, buf ^ 1);
        bf16x8 a0 = *(const bf16x8*)(ap0 + s * 32);
        bf16x8 a1 = *(const bf16x8*)(ap1 + s * 32);
        const char* bb = (const char*)bls[buf];
        #pragma unroll
        for (int nt = 0; nt < 16; ++nt) {
            bf16x8 bfr = *(const bf16x8*)(bb + nt * 1024 + l * 16);
            acc[0][nt] = __builtin_amdgcn_mfma_f32_16x16x32_bf16(a0, bfr, acc[0][nt], 0, 0, 0);
            acc[1][nt] = __builtin_amdgcn_mfma_f32_16x16x32_bf16(a1, bfr, acc[1][nt], 0, 0, 0);
        }
        VMW(0); __syncthreads();
        buf ^= 1;
    }
#undef STAGEX

    #pragma unroll
    for (int nt = 0; nt < 16; ++nt) {
        const int col = colb + nt * 16 + l15;
        const float bo = bp[col];
        #pragma unroll
        for (int mt = 0; mt < 2; ++mt)
            #pragma unroll
            for (int rg = 0; rg < 4; ++rg) {
                const int row = rowb + mt * 16 + lh * 4 + rg;
                Xg[(size_t)row * 4096 + col] = f2bf(acc[mt][nt][rg] + bo);
            }
    }
}

// ---------------- segment-parallel LSTM: coalesced stores + reg prefetch -----
// r17 was write-amplification + latency bound (WRITE 213MB vs ~100 logical,
// 830 GB/s effective). (1) pack-permutation makes each lane's 4 cells CONTIGUOUS
// true units -> u64/u64x2 write-through stores (full 64B lines per row).
// (2) A/xg/cprev register double-buffer across the (barrier-free) tile loop.
__global__ __launch_bounds__(256, 1) void lstm_seg(
    const u16* __restrict__ Xg,      // [16384][4096] bf16, PACKED unit order
    const u16* __restrict__ Wp,      // [4096][1536]
    const float* __restrict__ cx,    // (N,T,H) fp32
    const u16* __restrict__ hxbf,    // [64][1024] bf16
    const u16* __restrict__ entries, // [4][4096] CSR by rel
    const u32* __restrict__ offs,    // [4][258]
    u16* __restrict__ hs,            // [64][256][1024] bf16 (out2 lower)
    float* __restrict__ cA,          // [32][256][1024] f32 (out2 upper, n<32)
    float* __restrict__ cB,          // [32][256][1024] f32 (ws, n>=32)
    float* __restrict__ c_final,     // [64][1024] f32
    u32* __restrict__ flags)         // [4][64] x16-spaced
{
    __shared__ u16 wls[65536];       // 128 KB: h-part weights, quarter-major
    const int tid = threadIdx.x;
    const int v = tid >> 6, l = tid & 63;
    const int l15 = l & 15, lh = l >> 4;
    const int u = blockIdx.x & 63, g = blockIdx.x >> 6;

    // preload weights [r13-proven]: wave v stages quarter v (rows u*64+v*16..+15)
    {
        const u16* src = Wp + (size_t)(u * 64 + v * 16 + l15) * 1536 + I_ + lh * 8;
        char* dst = (char*)wls + v * 32768;
        #pragma unroll
        for (int kk = 0; kk < 32; ++kk)
            gload_lds16n(src + kk * 32, dst + kk * 1024);
    }

    const u16* gent = entries + g * 4096;
    const u32* goff = offs + g * 258;
    u32* gflags = flags + g * 64 * 16;
    const char* wlsb = (const char*)wls;

    VMW(0);
    __syncthreads();

    // ---- s = 0: elementwise rows; thread owns TRUE units (jt, jt+1) ----
    {
        const int m0 = (int)goff[1];
        const int gtid = u * 256 + tid;       // 0..16383 within group
        for (int cell = gtid; cell < m0 * 512; cell += 64 * 256) {
            const int ri = cell >> 9, jj = cell & 511;
            const int jt = jj * 2;
            const u16 e = gent[ri];
            const int t = e >> 6, n = e & 63;
            const int loc = jt & 15;
            const int jp = (jt & ~15) + ((loc & 3) << 2) + (loc >> 2);
            const u16* xrow = Xg + ((size_t)t * 64 + n) * 4096;
            const u16x4 xa = *(const u16x4*)(xrow + 4 * jp);
            const u16x4 xb = *(const u16x4*)(xrow + 4 * jp + 16);
            const float c0 = sigf(bf2f(xa[0])) * tanhfast(bf2f(xa[2]));
            const float h0 = sigf(bf2f(xa[3])) * tanhfast(c0);
            const float c1 = sigf(bf2f(xb[0])) * tanhfast(bf2f(xb[2]));
            const float h1 = sigf(bf2f(xb[3])) * tanhfast(c1);
            const size_t hrow = ((size_t)n * 256 + t) * 1024;
            __hip_atomic_store((u32*)(hs + hrow + jt),
                               (u32)f2bf(h0) | ((u32)f2bf(h1) << 16),
                               __ATOMIC_RELAXED, __HIP_MEMORY_SCOPE_AGENT);
            const u64 cpk = (u64)__float_as_uint(c0) | ((u64)__float_as_uint(c1) << 32);
            __hip_atomic_store((u64*)c_ptr(n, t, jt, cA, cB), cpk,
                               __ATOMIC_RELAXED, __HIP_MEMORY_SCOPE_AGENT);
            if (t == T_ - 1) *(float2*)(c_final + n * H_ + jt) = float2{c0, c1};
        }
    }
    VMW(0);
    __syncthreads();
    if (tid == 0)
        __hip_atomic_store(gflags + u * 16, 1u,
                           __ATOMIC_RELAXED, __HIP_MEMORY_SCOPE_AGENT);
    if (tid < 64) {
        while (__hip_atomic_load(gflags + tid * 16, __ATOMIC_RELAXED,
                                 __HIP_MEMORY_SCOPE_AGENT) < 1u)
            __builtin_amdgcn_s_sleep(1);
    }
    __syncthreads();
    __builtin_amdgcn_sched_barrier(0);

    // double-buffer state
    bf16x8 Aa[32], Ba[32];
    u16x4 Axg[4], Bxg[4];
    float Acp[4], Bcp[4];
    int At = 0, An = 0, Bt = 0, Bn = 0;
    bool Av = false, Bv = false;

#define LOADT(P, MT) do { \
    const int ridx_ = base + (MT) * 16 + l15; \
    P##v = (ridx_ <= last); \
    const u16 e_ = gent[P##v ? ridx_ : last]; \
    P##t = e_ >> 6; P##n = e_ & 63; \
    const u16* rowsrc_ = (P##t == 0) ? (hxbf + P##n * 1024) \
                       : (hs + ((size_t)P##n * 256 + (P##t - 1)) * 1024); \
    const char* lsrc_ = (const char*)rowsrc_ + lh * 16; \
    _Pragma("unroll") \
    for (int kk_ = 0; kk_ < 32; ++kk_) \
        P##a[kk_] = *(const bf16x8*)(lsrc_ + kk_ * 64); \
    const u16* xrow_ = Xg + ((size_t)P##t * 64 + P##n) * 4096; \
    _Pragma("unroll") \
    for (int q_ = 0; q_ < 4; ++q_) { \
        P##xg[q_] = *(const u16x4*)(xrow_ + 4 * (u * 16 + q_ * 4 + lh)); \
        const int jt_ = u * 16 + lh * 4 + q_; \
        P##cp[q_] = (P##t == 0) ? cx[(size_t)P##n * T_ * H_ + jt_] \
                                : *c_ptr(P##n, P##t - 1, jt_, cA, cB); \
    } \
} while (0)

#define PROCT(P) do { \
    f32x4 acc_[4]; \
    _Pragma("unroll") \
    for (int q_ = 0; q_ < 4; ++q_) acc_[q_] = f32x4{0.f, 0.f, 0.f, 0.f}; \
    _Pragma("unroll") \
    for (int q_ = 0; q_ < 4; ++q_) { \
        _Pragma("unroll") \
        for (int kk_ = 0; kk_ < 32; ++kk_) { \
            bf16x8 wf_ = *(const bf16x8*)(wlsb + q_ * 32768 + kk_ * 1024 + l * 16); \
            acc_[q_] = __builtin_amdgcn_mfma_f32_16x16x32_bf16(wf_, P##a[kk_], acc_[q_], 0, 0, 0); \
        } \
    } \
    float cn_[4], hv_[4]; \
    _Pragma("unroll") \
    for (int q_ = 0; q_ < 4; ++q_) { \
        const float ig_ = acc_[q_][0] + bf2f(P##xg[q_][0]); \
        const float fg_ = acc_[q_][1] + bf2f(P##xg[q_][1]); \
        const float gg_ = acc_[q_][2] + bf2f(P##xg[q_][2]); \
        const float og_ = acc_[q_][3] + bf2f(P##xg[q_][3]); \
        cn_[q_] = sigf(fg_) * P##cp[q_] + sigf(ig_) * tanhfast(gg_); \
        hv_[q_] = sigf(og_) * tanhfast(cn_[q_]); \
    } \
    if (P##v) { \
        const int jt0_ = u * 16 + lh * 4; \
        const u64 hp_ = (u64)f2bf(hv_[0]) | ((u64)f2bf(hv_[1]) << 16) \
                      | ((u64)f2bf(hv_[2]) << 32) | ((u64)f2bf(hv_[3]) << 48); \
        __hip_atomic_store((u64*)(hs + ((size_t)P##n * 256 + P##t) * 1024 + jt0_), \
                           hp_, __ATOMIC_RELAXED, __HIP_MEMORY_SCOPE_AGENT); \
        float* cp0_ = c_ptr(P##n, P##t, jt0_, cA, cB); \
        const u64 c01_ = (u64)__float_as_uint(cn_[0]) | ((u64)__float_as_uint(cn_[1]) << 32); \
        const u64 c23_ = (u64)__float_as_uint(cn_[2]) | ((u64)__float_as_uint(cn_[3]) << 32); \
        __hip_atomic_store((u64*)cp0_, c01_, __ATOMIC_RELAXED, __HIP_MEMORY_SCOPE_AGENT); \
        __hip_atomic_store((u64*)(cp0_ + 2), c23_, __ATOMIC_RELAXED, __HIP_MEMORY_SCOPE_AGENT); \
        if (P##t == T_ - 1) \
            *(float4*)(c_final + P##n * H_ + jt0_) = float4{cn_[0], cn_[1], cn_[2], cn_[3]}; \
    } \
} while (0)

    // ---- iterations s = 1.. (exact bound: rows with rel >= s exist)
    for (int s = 1; s <= 256; ++s) {
        if (goff[s] >= 4096u) break;
        const int base = (int)goff[s];
        const int last = (int)goff[s + 1] - 1;
        const int ntiles = ((last + 1 - base) + 15) >> 4;

        int mt = v;
        if (mt < ntiles) {
            LOADT(A, mt);
            while (true) {
                int nx = mt + 4;
                if (nx < ntiles) LOADT(B, nx);
                PROCT(A);
                mt = nx;
                if (mt >= ntiles) break;
                nx = mt + 4;
                if (nx < ntiles) LOADT(A, nx);
                PROCT(B);
                mt = nx;
                if (mt >= ntiles) break;
            }
        }

        // group barrier: phase s complete
        VMW(0);
        __syncthreads();
        if (tid == 0)
            __hip_atomic_store(gflags + u * 16, (u32)(s + 1),
                               __ATOMIC_RELAXED, __HIP_MEMORY_SCOPE_AGENT);
        if (tid < 64) {
            while (__hip_atomic_load(gflags + tid * 16, __ATOMIC_RELAXED,
                                     __HIP_MEMORY_SCOPE_AGENT) < (u32)(s + 1))
                __builtin_amdgcn_s_sleep(1);
        }
        __syncthreads();
        __builtin_amdgcn_sched_barrier(0);
    }
#undef LOADT
#undef PROCT
}

// ---------------- output projection: 256x256-tile GEMM + mish [proven r11] ---
__global__ __launch_bounds__(512) __attribute__((amdgpu_waves_per_eu(2, 2)))
void out_proj_mfma(
    const u16* __restrict__ hs,     // [16384][1024]
    const u16* __restrict__ Wo,     // [1024][1024]
    const float* __restrict__ b_out,
    float* __restrict__ out0)       // [16384][1024]
{
    __shared__ u16 bls[2][8192];    // 2 x 16KB
    const int bx = blockIdx.x, by = blockIdx.y;
    const int tid = threadIdx.x;
    const int v = tid >> 6, l = tid & 63;
    const int l15 = l & 15, lh = l >> 4;
    const int rowb = bx * 256 + v * 32;
    const int colb = by * 256;

    const u16* ap0 = hs + (size_t)(rowb + l15) * H_ + lh * 8;
    const u16* ap1 = hs + (size_t)(rowb + 16 + l15) * H_ + lh * 8;
    const u16* bs0 = Wo + (size_t)(colb + (2 * v) * 16 + l15) * H_ + lh * 8;
    const u16* bs1 = Wo + (size_t)(colb + (2 * v + 1) * 16 + l15) * H_ + lh * 8;

    f32x4 acc[2][16];
    #pragma unroll
    for (int m = 0; m < 2; ++m)
        #pragma unroll
        for (int nt = 0; nt < 16; ++nt) acc[m][nt] = f32x4{0.f, 0.f, 0.f, 0.f};

#define STAGEO(S, B) do { \
    gload_lds16n(bs0 + (S) * 32, (char*)bls[B] + (2 * v) * 1024); \
    gload_lds16n(bs1 + (S) * 32, (char*)bls[B] + (2 * v + 1) * 1024); } while (0)

    STAGEO(0, 0);
    VMW(0); __syncthreads();
    int buf = 0;
    for (int s = 0; s < 32; ++s) {
        if (s < 31) STAGEO(s + 1, buf ^ 1);
        bf16x8 a0 = *(const bf16x8*)(ap0 + s * 32);
        bf16x8 a1 = *(const bf16x8*)(ap1 + s * 32);
        const char* bb = (const char*)bls[buf];
        #pragma unroll
        for (int nt = 0; nt < 16; ++nt) {
            bf16x8 bfr = *(const bf16x8*)(bb + nt * 1024 + l * 16);
            acc[0][nt] = __builtin_amdgcn_mfma_f32_16x16x32_bf16(a0, bfr, acc[0][nt], 0, 0, 0);
            acc[1][nt] = __builtin_amdgcn_mfma_f32_16x16x32_bf16(a1, bfr, acc[1][nt], 0, 0, 0);
        }
        VMW(0); __syncthreads();
        buf ^= 1;
    }
#undef STAGEO

    #pragma unroll
    for (int nt = 0; nt < 16; ++nt) {
        const int col = colb + nt * 16 + l15;
        const float bo = b_out[col];
        #pragma unroll
        for (int mt = 0; mt < 2; ++mt)
            #pragma unroll
            for (int rg = 0; rg < 4; ++rg) {
                const int row = rowb + mt * 16 + lh * 4 + rg;
                const float y = acc[mt][nt][rg] + bo;
                const float sp = (y > 15.f) ? y : log1pf(__expf(y));
                out0[(size_t)row * H_ + col] = y * tanhfast(sp);
            }
    }
}

// out1 = broadcast hs[:,255,:]  (hs in out2 region — MUST run before bcast_c)
__global__ __launch_bounds__(256) void bcast_h(
    const u16* __restrict__ hs, float* __restrict__ out1)
{
    const size_t total = (size_t)N_ * T_ * H_;
    for (size_t idx = (size_t)blockIdx.x * 256 + threadIdx.x; idx < total;
         idx += (size_t)gridDim.x * 256) {
        const int n = (int)(idx >> 18);
        const int j = (int)(idx & (H_ - 1));
        out1[idx] = bf2f(hs[((size_t)n * T_ + (T_ - 1)) * H_ + j]);
    }
}

__global__ __launch_bounds__(256) void bcast_c(
    const float* __restrict__ c_final, float* __restrict__ out2)
{
    const size_t total = (size_t)N_ * T_ * H_;
    for (size_t idx = (size_t)blockIdx.x * 256 + threadIdx.x; idx < total;
         idx += (size_t)gridDim.x * 256) {
        const int n = (int)(idx >> 18);
        const int j = (int)(idx & (H_ - 1));
        out2[idx] = c_final[n * H_ + j];
    }
}

extern "C" void kernel_launch(void* const* d_in, const int* in_sizes, int n_in,
                              void* d_out, int out_size, void* d_ws, size_t ws_size,
                              hipStream_t stream) {
    const float* x      = (const float*)d_in[0];
    const int*   is_ini = (const int*)  d_in[1];
    const float* hx     = (const float*)d_in[2];
    const float* cx     = (const float*)d_in[3];
    const float* W_ih   = (const float*)d_in[4];
    const float* W_hh   = (const float*)d_in[5];
    const float* b_ih   = (const float*)d_in[6];
    const float* b_hh   = (const float*)d_in[7];
    const float* W_out  = (const float*)d_in[8];
    const float* b_out  = (const float*)d_in[9];

    float* out0 = (float*)d_out;
    float* out1 = out0 + (size_t)N_ * T_ * H_;
    float* out2 = out1 + (size_t)N_ * T_ * H_;

    char* ws = (char*)d_ws;
    u16*   x_tb    = (u16*)  (ws + 0);          // 16,777,216
    u16*   Wp      = (u16*)  (ws + 16777216);   // 12,582,912
    float* bp      = (float*)(ws + 29360128);   // 16,384
    u16*   Wo_b    = (u16*)  (ws + 29376512);   // 2,097,152
    float* c_final = (float*)(ws + 31473664);   // 262,144
    u16*   hxbf    = (u16*)  (ws + 31735808);   // 131,072
    u16*   rel16   = (u16*)  (ws + 31866880);   // 32,768
    u16*   entries = (u16*)  (ws + 31899648);   // 32,768
    u32*   offs    = (u32*)  (ws + 31932416);   // 4,352 (pad)
    u32*   flags   = (u32*)  (ws + 31945472);   // 16,384   [4][64] x16-spaced
    float* cB      = (float*)(ws + 31961856);   // 33,554,432 (c for n>=32)
                                                // ws end ~65.5 MB (r2-proven size)

    u16*   Xg = (u16*)out0;             // 134.2 MB scratch (out0+out1), consumed
    u16*   hs = (u16*)out2;             // 33.55 MB (out2 lower half)
    float* cA = (float*)(out2 + (size_t)32 * 256 * 1024);  // out2 upper (n<32)

    hipMemsetAsync(flags, 0, 16384, stream);
    pack_weights<<<4096, 256, 0, stream>>>(W_ih, W_hh, b_ih, b_hh, Wp, bp);
    conv_x<<<dim3(T_, N_), 256, 0, stream>>>(x, x_tb);
    conv_wout<<<1024, 256, 0, stream>>>(W_out, Wo_b);
    conv_hx<<<256, 256, 0, stream>>>(hx, hxbf);
    prep_rel<<<64, 256, 0, stream>>>(is_ini, rel16);
    prep_bucket<<<4, 256, 0, stream>>>(rel16, entries, offs);

    xgates_mfma<<<dim3(64, 16), 512, 0, stream>>>(x_tb, Wp, bp, Xg);

    lstm_seg<<<256, 256, 0, stream>>>(Xg, Wp, cx, hxbf, entries, offs,
                                      hs, cA, cB, c_final, flags);

    out_proj_mfma<<<dim3(64, 4), 512, 0, stream>>>(hs, Wo_b, b_out, out0);
    bcast_h<<<2048, 256, 0, stream>>>(hs, out1);
    bcast_c<<<2048, 256, 0, stream>>>(c_final, out2);
}